// Round 9
// baseline (988.939 us; speedup 1.0000x reference)
//
#include <hip/hip_runtime.h>
#include <hip/hip_bf16.h>
#include <math.h>

typedef unsigned short u16;
typedef __attribute__((ext_vector_type(8))) short bf16x8;
typedef __attribute__((ext_vector_type(4))) float f32x4;
typedef __attribute__((address_space(1))) unsigned int gu32;
typedef __attribute__((address_space(3))) unsigned int lu32;

#define DD 1024
#define PP 32

__device__ __forceinline__ u16 f2bf(float f) {
  unsigned u = __float_as_uint(f);
  unsigned r = u + 0x7fffu + ((u >> 16) & 1u);
  return (u16)(r >> 16);
}
__device__ __forceinline__ float bf2f(u16 h) {
  return __uint_as_float(((unsigned)h) << 16);
}

// ---------------- conversions ----------------
__global__ __launch_bounds__(256) void k_convert_x(const float* __restrict__ x,
                                                   u16* __restrict__ comb, int n4) {
  for (int i = blockIdx.x * 256 + threadIdx.x; i < n4; i += gridDim.x * 256) {
    float4 v = ((const float4*)x)[i];
    int row = i >> 8;
    int c4  = i & 255;
    ushort4 o;
    o.x = f2bf(v.x); o.y = f2bf(v.y); o.z = f2bf(v.z); o.w = f2bf(v.w);
    *(ushort4*)(comb + ((size_t)row << 11) + (c4 << 2)) = o;
  }
}

__global__ __launch_bounds__(256) void k_convert(const float* __restrict__ in,
                                                 u16* __restrict__ out, int n4) {
  for (int i = blockIdx.x * 256 + threadIdx.x; i < n4; i += gridDim.x * 256) {
    float4 v = ((const float4*)in)[i];
    ushort4 o;
    o.x = f2bf(v.x); o.y = f2bf(v.y); o.z = f2bf(v.z); o.w = f2bf(v.w);
    ((ushort4*)out)[i] = o;
  }
}

__global__ __launch_bounds__(256) void k_proto_prep(const float* __restrict__ protos,
                                                    u16* __restrict__ pb) {
  __shared__ float sb[4];
  int row = blockIdx.x, tid = threadIdx.x;
  float4 v = ((const float4*)(protos + row * DD))[tid];
  float q = v.x * v.x + v.y * v.y + v.z * v.z + v.w * v.w;
#pragma unroll
  for (int off = 32; off; off >>= 1) q += __shfl_xor(q, off);
  if ((tid & 63) == 0) sb[tid >> 6] = q;
  __syncthreads();
  q = sb[0] + sb[1] + sb[2] + sb[3];
  float inv = 1.0f / fmaxf(sqrtf(q), 1e-12f);
  ushort4 o;
  o.x = f2bf(v.x * inv); o.y = f2bf(v.y * inv); o.z = f2bf(v.z * inv); o.w = f2bf(v.w * inv);
  ((ushort4*)(pb + row * DD))[tid] = o;
}

__global__ __launch_bounds__(256) void k_protoT(const float* __restrict__ protos,
                                                u16* __restrict__ pbT) {
  int i = blockIdx.x * 256 + threadIdx.x;
  if (i < DD * PP) {
    int p = i & 31, d = i >> 5;
    pbT[i] = f2bf(protos[p * DD + d]);
  }
}

// ---------------- 128x128 bf16 GEMM (B^T layout), T2 swizzle, merged sync ----------------
// 256 threads = 4 waves (2x2) of 64x64. LDS = 2 x (A 16KB + B 16KB) = 64KB
// -> 2 blocks/CU = 2 independent barrier domains (LDS/MFMA pipes anti-phase).
// One barrier + one vmcnt(0) per K-tile; body T stages tile T+1 into buf^1.
#define GLL(gsrc, ldst) __builtin_amdgcn_global_load_lds((gu32*)(gsrc), (lu32*)(ldst), 16, 0, 0)

template <int EPI>
__global__ __launch_bounds__(256, 2) void k_gemm8(const u16* __restrict__ A, int lda,
                                                  const u16* __restrict__ Bm,
                                                  const float* __restrict__ bias,
                                                  const u16* __restrict__ residb,
                                                  void* __restrict__ Cout, int ldc,
                                                  int K, int nbn) {
  __shared__ u16 Als[2][128 * 64];
  __shared__ u16 Bls[2][128 * 64];
  const int tid = threadIdx.x;
  const int wid = tid >> 6, lane = tid & 63;
  const int wm = wid >> 1, wn = wid & 1;
  const int lm = lane & 15, lk = lane >> 4;
  const int NT = K >> 6;

  // staging source-column swizzle (u16 units): chunk (lane&7) XOR row-in-group (lane>>3)
  const int scol_sw = (((lane & 7) ^ ((lane >> 3) & 7)) << 3);
  const int srow = lane >> 3;

  // XCD chunked swizzle (nwg % 8 == 0)
  int g = blockIdx.x;
  int cpx = gridDim.x >> 3;
  int lin = (g & 7) * cpx + (g >> 3);
  int bn = lin % nbn, bm = lin / nbn;
  const size_t bmBase = (size_t)bm * 128;
  const size_t bnBase = (size_t)bn * 128;

  f32x4 acc[4][4];
#pragma unroll
  for (int i = 0; i < 4; ++i)
#pragma unroll
    for (int j = 0; j < 4; ++j) acc[i][j] = (f32x4){0.f, 0.f, 0.f, 0.f};

  bf16x8 a[4][2], b[4][2];

  // stage the full 128x64 A-tile: 4 GLL per wave (rows j*32 + wid*8 .. +7)
#define STAGE_A(bufv, kt) do {                                                  \
    _Pragma("unroll") for (int j = 0; j < 4; ++j)                               \
      GLL(A + (bmBase + j * 32 + wid * 8 + srow) * lda + scol_sw + (kt) * 64,   \
          &Als[bufv][(j * 32 + wid * 8) * 64]);                                 \
  } while (0)

#define STAGE_B(bufv, kt) do {                                                  \
    _Pragma("unroll") for (int j = 0; j < 4; ++j)                               \
      GLL(Bm + (bnBase + j * 32 + wid * 8 + srow) * (size_t)K + scol_sw + (kt) * 64, \
          &Bls[bufv][(j * 32 + wid * 8) * 64]);                                 \
  } while (0)

#define LOAD_A(bufv) do {                                                       \
    _Pragma("unroll") for (int mi2 = 0; mi2 < 4; ++mi2) {                       \
      int row = wm * 64 + mi2 * 16 + lm;                                        \
      _Pragma("unroll") for (int kk = 0; kk < 2; ++kk)                          \
        a[mi2][kk] = *(const bf16x8*)&Als[bufv][row * 64 + ((kk * 32 + lk * 8) ^ ((lm & 7) << 3))]; \
    }                                                                           \
  } while (0)

#define LOAD_B(bufv) do {                                                       \
    _Pragma("unroll") for (int ni2 = 0; ni2 < 4; ++ni2) {                       \
      int row = wn * 64 + ni2 * 16 + lm;                                        \
      _Pragma("unroll") for (int kk = 0; kk < 2; ++kk)                          \
        b[ni2][kk] = *(const bf16x8*)&Bls[bufv][row * 64 + ((kk * 32 + lk * 8) ^ ((lm & 7) << 3))]; \
    }                                                                           \
  } while (0)

#define BARRIER do { __builtin_amdgcn_s_barrier(); asm volatile("" ::: "memory"); } while (0)

#define MFMA_ALL do {                                                           \
    __builtin_amdgcn_s_setprio(1);                                              \
    _Pragma("unroll") for (int mi2 = 0; mi2 < 4; ++mi2)                         \
    _Pragma("unroll") for (int ni2 = 0; ni2 < 4; ++ni2)                         \
    _Pragma("unroll") for (int kk = 0; kk < 2; ++kk)                            \
      acc[mi2][ni2] = __builtin_amdgcn_mfma_f32_16x16x32_bf16(                  \
          a[mi2][kk], b[ni2][kk], acc[mi2][ni2], 0, 0, 0);                      \
    __builtin_amdgcn_s_setprio(0);                                              \
  } while (0)

  // one barrier + one vmcnt per K-tile; all stages for T+1 target buf^1
#define TILE(T, P) do {                                                         \
    asm volatile("s_waitcnt vmcnt(0)" ::: "memory");                            \
    BARRIER;                                                                    \
    if ((T) + 1 < NT) { STAGE_A((P) ^ 1, (T) + 1); STAGE_B((P) ^ 1, (T) + 1); } \
    LOAD_A(P); LOAD_B(P);                                                       \
    MFMA_ALL;                                                                   \
  } while (0)

  // prologue: stage tile0 into buf0
  STAGE_A(0, 0); STAGE_B(0, 0);

  for (int T = 0; T < NT; T += 2) {
    TILE(T, 0);
    TILE(T + 1, 1);
  }

  // epilogue: C/D layout col = lane&15 (n), row = (lane>>4)*4 + r (m)
  const int rbase = lk * 4;
  const size_t gr0 = bmBase + wm * 64;
  const int gc0 = (int)bnBase + wn * 64;
#pragma unroll
  for (int mi = 0; mi < 4; ++mi) {
#pragma unroll
    for (int ni = 0; ni < 4; ++ni) {
      int gcol = gc0 + ni * 16 + lm;
      float bv = bias[gcol];
#pragma unroll
      for (int r = 0; r < 4; ++r) {
        size_t grow = gr0 + mi * 16 + rbase + r;
        float v = acc[mi][ni][r] + bv;
        if (EPI == 0) {
          ((u16*)Cout)[grow * ldc + gcol] = f2bf(v);
        } else {
          float gl = 0.5f * v * (1.0f + erff(v * 0.70710678118654752f));
          float y = gl + bf2f(residb[grow * 2048 + gcol]);
          ((float*)Cout)[grow * ldc + gcol] = y;
        }
      }
    }
  }
#undef STAGE_A
#undef STAGE_B
#undef LOAD_A
#undef LOAD_B
#undef MFMA_ALL
#undef TILE
#undef BARRIER
}

// ---------------- fused: sim (MFMA) -> softmax -> retrieved (MFMA) ----------------
__global__ __launch_bounds__(256) void k_mid(const u16* __restrict__ h,
                                             const u16* __restrict__ pb,
                                             const u16* __restrict__ pbT,
                                             u16* __restrict__ comb) {
  __shared__ u16 attn_sm[4][16 * 32];
  const int tid = threadIdx.x;
  const int w = tid >> 6, lane = tid & 63;
  const int lm = lane & 15, lk = lane >> 4;
  const int row0 = blockIdx.x * 64 + w * 16;

  f32x4 zero = {0.f, 0.f, 0.f, 0.f};
  f32x4 acc0 = zero, acc1 = zero;
  float ss = 0.f;

  const u16* hrow = h + ((size_t)(row0 + lm) << 10) + lk * 8;
  const u16* pb0 = pb + (size_t)lm * DD + lk * 8;
  const u16* pb1 = pb + (size_t)(16 + lm) * DD + lk * 8;
#pragma unroll 4
  for (int k0 = 0; k0 < DD; k0 += 32) {
    bf16x8 af = *(const bf16x8*)(hrow + k0);
    bf16x8 b0 = *(const bf16x8*)(pb0 + k0);
    bf16x8 b1 = *(const bf16x8*)(pb1 + k0);
    acc0 = __builtin_amdgcn_mfma_f32_16x16x32_bf16(af, b0, acc0, 0, 0, 0);
    acc1 = __builtin_amdgcn_mfma_f32_16x16x32_bf16(af, b1, acc1, 0, 0, 0);
#pragma unroll
    for (int j = 0; j < 8; ++j) {
      float hv = bf2f((u16)af[j]);
      ss += hv * hv;
    }
  }
  ss += __shfl_xor(ss, 16);
  ss += __shfl_xor(ss, 32);
  float inv = 10.0f / fmaxf(sqrtf(ss), 1e-12f);

  float a0[4], a1[4];
#pragma unroll
  for (int r = 0; r < 4; ++r) {
    float invr = __shfl(inv, lk * 4 + r);
    float s0 = acc0[r] * invr;
    float s1 = acc1[r] * invr;
    float mr = fmaxf(s0, s1);
#pragma unroll
    for (int off = 1; off < 16; off <<= 1) mr = fmaxf(mr, __shfl_xor(mr, off));
    float e0 = expf(s0 - mr);
    float e1 = expf(s1 - mr);
    float sum = e0 + e1;
#pragma unroll
    for (int off = 1; off < 16; off <<= 1) sum += __shfl_xor(sum, off);
    float rs = 1.0f / sum;
    a0[r] = e0 * rs;
    a1[r] = e1 * rs;
  }

  u16* as = attn_sm[w];
#pragma unroll
  for (int r = 0; r < 4; ++r) {
    as[(lk * 4 + r) * 32 + lm] = f2bf(a0[r]);
    as[(lk * 4 + r) * 32 + 16 + lm] = f2bf(a1[r]);
  }
  __syncthreads();
  bf16x8 battn = *(const bf16x8*)(as + lm * 32 + lk * 8);

  u16* crow = comb + ((size_t)(row0 + lm) << 11) + DD;
#pragma unroll 4
  for (int d0 = 0; d0 < DD; d0 += 16) {
    bf16x8 ap = *(const bf16x8*)(pbT + (size_t)(d0 + lm) * PP + lk * 8);
    f32x4 rc = __builtin_amdgcn_mfma_f32_16x16x32_bf16(ap, battn, zero, 0, 0, 0);
    ushort4 o;
    o.x = f2bf(rc[0]); o.y = f2bf(rc[1]); o.z = f2bf(rc[2]); o.w = f2bf(rc[3]);
    *(ushort4*)(crow + d0 + lk * 4) = o;
  }
}

// ---------------- in-place LayerNorm over rows of 1024 ----------------
__global__ __launch_bounds__(256) void k_ln(float* __restrict__ io,
                                            const float* __restrict__ gamma,
                                            const float* __restrict__ beta) {
  __shared__ float sb[8];
  size_t row = blockIdx.x;
  float4* rp = (float4*)(io + (row << 10));
  int tid = threadIdx.x;
  float4 v = rp[tid];
  float s = v.x + v.y + v.z + v.w;
  float q = v.x * v.x + v.y * v.y + v.z * v.z + v.w * v.w;
#pragma unroll
  for (int off = 32; off; off >>= 1) { s += __shfl_xor(s, off); q += __shfl_xor(q, off); }
  if ((tid & 63) == 0) { sb[tid >> 6] = s; sb[4 + (tid >> 6)] = q; }
  __syncthreads();
  s = sb[0] + sb[1] + sb[2] + sb[3];
  q = sb[4] + sb[5] + sb[6] + sb[7];
  float mu = s * (1.f / 1024.f);
  float var = q * (1.f / 1024.f) - mu * mu;
  float rstd = rsqrtf(var + 1e-5f);
  float4 g = ((const float4*)gamma)[tid];
  float4 b = ((const float4*)beta)[tid];
  v.x = (v.x - mu) * rstd * g.x + b.x;
  v.y = (v.y - mu) * rstd * g.y + b.y;
  v.z = (v.z - mu) * rstd * g.z + b.z;
  v.w = (v.w - mu) * rstd * g.w + b.w;
  rp[tid] = v;
}

extern "C" void kernel_launch(void* const* d_in, const int* in_sizes, int n_in,
                              void* d_out, int out_size, void* d_ws, size_t ws_size,
                              hipStream_t stream) {
  const float* x      = (const float*)d_in[0];
  const float* Wi     = (const float*)d_in[1];
  const float* bi     = (const float*)d_in[2];
  const float* Wo     = (const float*)d_in[3];
  const float* bo     = (const float*)d_in[4];
  const float* gamma  = (const float*)d_in[5];
  const float* beta   = (const float*)d_in[6];
  const float* protos = (const float*)d_in[7];
  const int Brows = in_sizes[0] / DD;  // 65536

  u16* comb = (u16*)d_ws;                        // [B, 2048] bf16
  u16* WiB  = comb + (size_t)Brows * 2048;       // [1024, 1024]
  u16* WoB  = WiB + (size_t)1024 * 1024;         // [1024, 2048]
  u16* pb   = WoB + (size_t)1024 * 2048;         // [32, 1024] normalized
  u16* pbT  = pb + (size_t)PP * DD;              // [1024, 32] raw transposed
  u16* hbuf = (u16*)d_out;                       // h bf16 lives in d_out storage

  k_convert_x<<<4096, 256, 0, stream>>>(x, comb, Brows * 256);
  k_convert<<<1024, 256, 0, stream>>>(Wi, WiB, 1024 * 1024 / 4);
  k_convert<<<2048, 256, 0, stream>>>(Wo, WoB, 1024 * 2048 / 4);
  k_proto_prep<<<PP, 256, 0, stream>>>(protos, pb);
  k_protoT<<<(DD * PP + 255) / 256, 256, 0, stream>>>(protos, pbT);

  const int nbn = 1024 / 128;                    // 8 col-blocks
  const int nwg = nbn * (Brows / 128);           // 4096 blocks

  // h = x @ Wi^T + bi
  k_gemm8<0><<<nwg, 256, 0, stream>>>(comb, 2048, WiB, bi, nullptr,
                                      (void*)hbuf, DD, DD, nbn);
  // fused sim -> softmax -> retrieved into combined right half
  k_mid<<<Brows / 64, 256, 0, stream>>>(hbuf, pb, pbT, comb);
  // y = gelu(combined @ Wo^T + bo) + bf16(x)  -> d_out (f32)
  k_gemm8<1><<<nwg, 256, 0, stream>>>(comb, 2048, WoB, bo, comb,
                                      d_out, DD, 2 * DD, nbn);
  // in-place LayerNorm
  k_ln<<<Brows, 256, 0, stream>>>((float*)d_out, gamma, beta);
}

// Round 10
// 979.653 us; speedup vs baseline: 1.0095x; 1.0095x over previous
//
#include <hip/hip_runtime.h>
#include <hip/hip_bf16.h>
#include <math.h>

typedef unsigned short u16;
typedef __attribute__((ext_vector_type(8))) short bf16x8;
typedef __attribute__((ext_vector_type(4))) float f32x4;
typedef __attribute__((address_space(1))) unsigned int gu32;
typedef __attribute__((address_space(3))) unsigned int lu32;

#define DD 1024
#define PP 32

__device__ __forceinline__ u16 f2bf(float f) {
  unsigned u = __float_as_uint(f);
  unsigned r = u + 0x7fffu + ((u >> 16) & 1u);
  return (u16)(r >> 16);
}
__device__ __forceinline__ float bf2f(u16 h) {
  return __uint_as_float(((unsigned)h) << 16);
}

// ---------------- conversions ----------------
__global__ __launch_bounds__(256) void k_convert_x(const float* __restrict__ x,
                                                   u16* __restrict__ comb, int n4) {
  for (int i = blockIdx.x * 256 + threadIdx.x; i < n4; i += gridDim.x * 256) {
    float4 v = ((const float4*)x)[i];
    int row = i >> 8;
    int c4  = i & 255;
    ushort4 o;
    o.x = f2bf(v.x); o.y = f2bf(v.y); o.z = f2bf(v.z); o.w = f2bf(v.w);
    *(ushort4*)(comb + ((size_t)row << 11) + (c4 << 2)) = o;
  }
}

__global__ __launch_bounds__(256) void k_convert(const float* __restrict__ in,
                                                 u16* __restrict__ out, int n4) {
  for (int i = blockIdx.x * 256 + threadIdx.x; i < n4; i += gridDim.x * 256) {
    float4 v = ((const float4*)in)[i];
    ushort4 o;
    o.x = f2bf(v.x); o.y = f2bf(v.y); o.z = f2bf(v.z); o.w = f2bf(v.w);
    ((ushort4*)out)[i] = o;
  }
}

__global__ __launch_bounds__(256) void k_proto_prep(const float* __restrict__ protos,
                                                    u16* __restrict__ pb) {
  __shared__ float sb[4];
  int row = blockIdx.x, tid = threadIdx.x;
  float4 v = ((const float4*)(protos + row * DD))[tid];
  float q = v.x * v.x + v.y * v.y + v.z * v.z + v.w * v.w;
#pragma unroll
  for (int off = 32; off; off >>= 1) q += __shfl_xor(q, off);
  if ((tid & 63) == 0) sb[tid >> 6] = q;
  __syncthreads();
  q = sb[0] + sb[1] + sb[2] + sb[3];
  float inv = 1.0f / fmaxf(sqrtf(q), 1e-12f);
  ushort4 o;
  o.x = f2bf(v.x * inv); o.y = f2bf(v.y * inv); o.z = f2bf(v.z * inv); o.w = f2bf(v.w * inv);
  ((ushort4*)(pb + row * DD))[tid] = o;
}

__global__ __launch_bounds__(256) void k_protoT(const float* __restrict__ protos,
                                                u16* __restrict__ pbT) {
  int i = blockIdx.x * 256 + threadIdx.x;
  if (i < DD * PP) {
    int p = i & 31, d = i >> 5;
    pbT[i] = f2bf(protos[p * DD + d]);
  }
}

// ---------------- m97-replica 128x128 bf16 GEMM (B^T layout) + T2/T1 swizzles ----------
// Single-buffered 32KB LDS, two __syncthreads per K-tile, NO explicit waitcnt/setprio —
// compiler schedules fine-grained lgkmcnt; overlap comes from 3-5 co-resident blocks.
// T2: source-column swizzle chunk' = chunk ^ (row&7) at staging + same XOR on ds_read.
#define GLL(gsrc, ldst) __builtin_amdgcn_global_load_lds((gu32*)(gsrc), (lu32*)(ldst), 16, 0, 0)

template <int EPI>
__global__ __launch_bounds__(256) void k_gemm97(const u16* __restrict__ A, int lda,
                                                const u16* __restrict__ Bm,
                                                const float* __restrict__ bias,
                                                const u16* __restrict__ residb,
                                                void* __restrict__ Cout, int ldc,
                                                int K, int nbn) {
  __shared__ u16 Als[128 * 64];
  __shared__ u16 Bls[128 * 64];
  const int tid = threadIdx.x;
  const int wid = tid >> 6, lane = tid & 63;
  const int wm = wid >> 1, wn = wid & 1;
  const int lm = lane & 15, lk = lane >> 4;
  const int NT = K >> 6;

  const int scol_sw = (((lane & 7) ^ ((lane >> 3) & 7)) << 3);  // u16 units
  const int srow = lane >> 3;

  // XCD chunked swizzle (nwg % 8 == 0): 8 bn-blocks sharing an A-panel stay on one XCD
  int g = blockIdx.x;
  int cpx = gridDim.x >> 3;
  int lin = (g & 7) * cpx + (g >> 3);
  int bn = lin % nbn, bm = lin / nbn;
  const size_t bmBase = (size_t)bm * 128;
  const size_t bnBase = (size_t)bn * 128;

  f32x4 acc[4][4];
#pragma unroll
  for (int i = 0; i < 4; ++i)
#pragma unroll
    for (int j = 0; j < 4; ++j) acc[i][j] = (f32x4){0.f, 0.f, 0.f, 0.f};

  for (int T = 0; T < NT; ++T) {
    // stage full 128x64 A and B tiles: 4 GLL each per wave
#pragma unroll
    for (int j = 0; j < 4; ++j) {
      GLL(A + (bmBase + j * 32 + wid * 8 + srow) * lda + scol_sw + T * 64,
          &Als[(j * 32 + wid * 8) * 64]);
      GLL(Bm + (bnBase + j * 32 + wid * 8 + srow) * (size_t)K + scol_sw + T * 64,
          &Bls[(j * 32 + wid * 8) * 64]);
    }
    __syncthreads();

    bf16x8 a[4][2], b[4][2];
#pragma unroll
    for (int mi2 = 0; mi2 < 4; ++mi2) {
      int row = wm * 64 + mi2 * 16 + lm;
#pragma unroll
      for (int kk = 0; kk < 2; ++kk)
        a[mi2][kk] = *(const bf16x8*)&Als[row * 64 + ((kk * 32 + lk * 8) ^ ((lm & 7) << 3))];
    }
#pragma unroll
    for (int ni2 = 0; ni2 < 4; ++ni2) {
      int row = wn * 64 + ni2 * 16 + lm;
#pragma unroll
      for (int kk = 0; kk < 2; ++kk)
        b[ni2][kk] = *(const bf16x8*)&Bls[row * 64 + ((kk * 32 + lk * 8) ^ ((lm & 7) << 3))];
    }
#pragma unroll
    for (int mi2 = 0; mi2 < 4; ++mi2)
#pragma unroll
      for (int ni2 = 0; ni2 < 4; ++ni2)
#pragma unroll
        for (int kk = 0; kk < 2; ++kk)
          acc[mi2][ni2] = __builtin_amdgcn_mfma_f32_16x16x32_bf16(
              a[mi2][kk], b[ni2][kk], acc[mi2][ni2], 0, 0, 0);
    __syncthreads();
  }

  // epilogue: C/D layout col = lane&15 (n), row = (lane>>4)*4 + r (m)
  const int rbase = lk * 4;
  const size_t gr0 = bmBase + wm * 64;
  const int gc0 = (int)bnBase + wn * 64;
#pragma unroll
  for (int mi = 0; mi < 4; ++mi) {
#pragma unroll
    for (int ni = 0; ni < 4; ++ni) {
      int gcol = gc0 + ni * 16 + lm;
      float bv = bias[gcol];
#pragma unroll
      for (int r = 0; r < 4; ++r) {
        size_t grow = gr0 + mi * 16 + rbase + r;
        float v = acc[mi][ni][r] + bv;
        if (EPI == 0) {
          ((u16*)Cout)[grow * ldc + gcol] = f2bf(v);
        } else {
          float gl = 0.5f * v * (1.0f + erff(v * 0.70710678118654752f));
          float y = gl + bf2f(residb[grow * 2048 + gcol]);
          ((float*)Cout)[grow * ldc + gcol] = y;
        }
      }
    }
  }
}

// ---------------- fused: sim (MFMA) -> softmax -> retrieved (MFMA) ----------------
__global__ __launch_bounds__(256) void k_mid(const u16* __restrict__ h,
                                             const u16* __restrict__ pb,
                                             const u16* __restrict__ pbT,
                                             u16* __restrict__ comb) {
  __shared__ u16 attn_sm[4][16 * 32];
  const int tid = threadIdx.x;
  const int w = tid >> 6, lane = tid & 63;
  const int lm = lane & 15, lk = lane >> 4;
  const int row0 = blockIdx.x * 64 + w * 16;

  f32x4 zero = {0.f, 0.f, 0.f, 0.f};
  f32x4 acc0 = zero, acc1 = zero;
  float ss = 0.f;

  const u16* hrow = h + ((size_t)(row0 + lm) << 10) + lk * 8;
  const u16* pb0 = pb + (size_t)lm * DD + lk * 8;
  const u16* pb1 = pb + (size_t)(16 + lm) * DD + lk * 8;
#pragma unroll 4
  for (int k0 = 0; k0 < DD; k0 += 32) {
    bf16x8 af = *(const bf16x8*)(hrow + k0);
    bf16x8 b0 = *(const bf16x8*)(pb0 + k0);
    bf16x8 b1 = *(const bf16x8*)(pb1 + k0);
    acc0 = __builtin_amdgcn_mfma_f32_16x16x32_bf16(af, b0, acc0, 0, 0, 0);
    acc1 = __builtin_amdgcn_mfma_f32_16x16x32_bf16(af, b1, acc1, 0, 0, 0);
#pragma unroll
    for (int j = 0; j < 8; ++j) {
      float hv = bf2f((u16)af[j]);
      ss += hv * hv;
    }
  }
  ss += __shfl_xor(ss, 16);
  ss += __shfl_xor(ss, 32);
  float inv = 10.0f / fmaxf(sqrtf(ss), 1e-12f);

  float a0[4], a1[4];
#pragma unroll
  for (int r = 0; r < 4; ++r) {
    float invr = __shfl(inv, lk * 4 + r);
    float s0 = acc0[r] * invr;
    float s1 = acc1[r] * invr;
    float mr = fmaxf(s0, s1);
#pragma unroll
    for (int off = 1; off < 16; off <<= 1) mr = fmaxf(mr, __shfl_xor(mr, off));
    float e0 = expf(s0 - mr);
    float e1 = expf(s1 - mr);
    float sum = e0 + e1;
#pragma unroll
    for (int off = 1; off < 16; off <<= 1) sum += __shfl_xor(sum, off);
    float rs = 1.0f / sum;
    a0[r] = e0 * rs;
    a1[r] = e1 * rs;
  }

  u16* as = attn_sm[w];
#pragma unroll
  for (int r = 0; r < 4; ++r) {
    as[(lk * 4 + r) * 32 + lm] = f2bf(a0[r]);
    as[(lk * 4 + r) * 32 + 16 + lm] = f2bf(a1[r]);
  }
  __syncthreads();
  bf16x8 battn = *(const bf16x8*)(as + lm * 32 + lk * 8);

  u16* crow = comb + ((size_t)(row0 + lm) << 11) + DD;
#pragma unroll 4
  for (int d0 = 0; d0 < DD; d0 += 16) {
    bf16x8 ap = *(const bf16x8*)(pbT + (size_t)(d0 + lm) * PP + lk * 8);
    f32x4 rc = __builtin_amdgcn_mfma_f32_16x16x32_bf16(ap, battn, zero, 0, 0, 0);
    ushort4 o;
    o.x = f2bf(rc[0]); o.y = f2bf(rc[1]); o.z = f2bf(rc[2]); o.w = f2bf(rc[3]);
    *(ushort4*)(crow + d0 + lk * 4) = o;
  }
}

// ---------------- in-place LayerNorm over rows of 1024 ----------------
__global__ __launch_bounds__(256) void k_ln(float* __restrict__ io,
                                            const float* __restrict__ gamma,
                                            const float* __restrict__ beta) {
  __shared__ float sb[8];
  size_t row = blockIdx.x;
  float4* rp = (float4*)(io + (row << 10));
  int tid = threadIdx.x;
  float4 v = rp[tid];
  float s = v.x + v.y + v.z + v.w;
  float q = v.x * v.x + v.y * v.y + v.z * v.z + v.w * v.w;
#pragma unroll
  for (int off = 32; off; off >>= 1) { s += __shfl_xor(s, off); q += __shfl_xor(q, off); }
  if ((tid & 63) == 0) { sb[tid >> 6] = s; sb[4 + (tid >> 6)] = q; }
  __syncthreads();
  s = sb[0] + sb[1] + sb[2] + sb[3];
  q = sb[4] + sb[5] + sb[6] + sb[7];
  float mu = s * (1.f / 1024.f);
  float var = q * (1.f / 1024.f) - mu * mu;
  float rstd = rsqrtf(var + 1e-5f);
  float4 g = ((const float4*)gamma)[tid];
  float4 b = ((const float4*)beta)[tid];
  v.x = (v.x - mu) * rstd * g.x + b.x;
  v.y = (v.y - mu) * rstd * g.y + b.y;
  v.z = (v.z - mu) * rstd * g.z + b.z;
  v.w = (v.w - mu) * rstd * g.w + b.w;
  rp[tid] = v;
}

extern "C" void kernel_launch(void* const* d_in, const int* in_sizes, int n_in,
                              void* d_out, int out_size, void* d_ws, size_t ws_size,
                              hipStream_t stream) {
  const float* x      = (const float*)d_in[0];
  const float* Wi     = (const float*)d_in[1];
  const float* bi     = (const float*)d_in[2];
  const float* Wo     = (const float*)d_in[3];
  const float* bo     = (const float*)d_in[4];
  const float* gamma  = (const float*)d_in[5];
  const float* beta   = (const float*)d_in[6];
  const float* protos = (const float*)d_in[7];
  const int Brows = in_sizes[0] / DD;  // 65536

  u16* comb = (u16*)d_ws;                        // [B, 2048] bf16
  u16* WiB  = comb + (size_t)Brows * 2048;       // [1024, 1024]
  u16* WoB  = WiB + (size_t)1024 * 1024;         // [1024, 2048]
  u16* pb   = WoB + (size_t)1024 * 2048;         // [32, 1024] normalized
  u16* pbT  = pb + (size_t)PP * DD;              // [1024, 32] raw transposed
  u16* hbuf = (u16*)d_out;                       // h bf16 lives in d_out storage

  k_convert_x<<<4096, 256, 0, stream>>>(x, comb, Brows * 256);
  k_convert<<<1024, 256, 0, stream>>>(Wi, WiB, 1024 * 1024 / 4);
  k_convert<<<2048, 256, 0, stream>>>(Wo, WoB, 1024 * 2048 / 4);
  k_proto_prep<<<PP, 256, 0, stream>>>(protos, pb);
  k_protoT<<<(DD * PP + 255) / 256, 256, 0, stream>>>(protos, pbT);

  const int nbn = 1024 / 128;                    // 8 col-blocks
  const int nwg = nbn * (Brows / 128);           // 4096 blocks

  // h = x @ Wi^T + bi
  k_gemm97<0><<<nwg, 256, 0, stream>>>(comb, 2048, WiB, bi, nullptr,
                                       (void*)hbuf, DD, DD, nbn);
  // fused sim -> softmax -> retrieved into combined right half
  k_mid<<<Brows / 64, 256, 0, stream>>>(hbuf, pb, pbT, comb);
  // y = gelu(combined @ Wo^T + bo) + bf16(x)  -> d_out (f32)
  k_gemm97<1><<<nwg, 256, 0, stream>>>(comb, 2048, WoB, bo, comb,
                                       d_out, DD, 2 * DD, nbn);
  // in-place LayerNorm
  k_ln<<<Brows, 256, 0, stream>>>((float*)d_out, gamma, beta);
}

// Round 11
// 727.742 us; speedup vs baseline: 1.3589x; 1.3462x over previous
//
#include <hip/hip_runtime.h>
#include <hip/hip_bf16.h>
#include <math.h>

typedef unsigned short u16;
typedef __attribute__((ext_vector_type(8))) short bf16x8;
typedef __attribute__((ext_vector_type(4))) float f32x4;
typedef __attribute__((address_space(1))) unsigned int gu32;
typedef __attribute__((address_space(3))) unsigned int lu32;

#define DD 1024
#define PP 32

__device__ __forceinline__ u16 f2bf(float f) {
  unsigned u = __float_as_uint(f);
  unsigned r = u + 0x7fffu + ((u >> 16) & 1u);
  return (u16)(r >> 16);
}
__device__ __forceinline__ float bf2f(u16 h) {
  return __uint_as_float(((unsigned)h) << 16);
}

// ---------------- conversions ----------------
__global__ __launch_bounds__(256) void k_convert(const float* __restrict__ in,
                                                 u16* __restrict__ out, int n4) {
  for (int i = blockIdx.x * 256 + threadIdx.x; i < n4; i += gridDim.x * 256) {
    float4 v = ((const float4*)in)[i];
    ushort4 o;
    o.x = f2bf(v.x); o.y = f2bf(v.y); o.z = f2bf(v.z); o.w = f2bf(v.w);
    ((ushort4*)out)[i] = o;
  }
}

// Wo [1024,2048] f32 -> WoB[n, 0:1024] bf16 (stride 1088)
__global__ __launch_bounds__(256) void k_convert_wo(const float* __restrict__ Wo,
                                                    u16* __restrict__ WoB) {
  int i = blockIdx.x * 256 + threadIdx.x;  // 1024*256
  int n = i >> 8, c4 = i & 255;
  float4 v = ((const float4*)(Wo + (size_t)n * 2048))[c4];
  ushort4 o;
  o.x = f2bf(v.x); o.y = f2bf(v.y); o.z = f2bf(v.z); o.w = f2bf(v.w);
  *(ushort4*)(WoB + (size_t)n * 1088 + c4 * 4) = o;
}

// prototypes [32,1024] f32 -> row-l2-normalized bf16 (for sim)
__global__ __launch_bounds__(256) void k_proto_prep(const float* __restrict__ protos,
                                                    u16* __restrict__ pb) {
  __shared__ float sb[4];
  int row = blockIdx.x, tid = threadIdx.x;
  float4 v = ((const float4*)(protos + row * DD))[tid];
  float q = v.x * v.x + v.y * v.y + v.z * v.z + v.w * v.w;
#pragma unroll
  for (int off = 32; off; off >>= 1) q += __shfl_xor(q, off);
  if ((tid & 63) == 0) sb[tid >> 6] = q;
  __syncthreads();
  q = sb[0] + sb[1] + sb[2] + sb[3];
  float inv = 1.0f / fmaxf(sqrtf(q), 1e-12f);
  ushort4 o;
  o.x = f2bf(v.x * inv); o.y = f2bf(v.y * inv); o.z = f2bf(v.z * inv); o.w = f2bf(v.w * inv);
  ((ushort4*)(pb + row * DD))[tid] = o;
}

// P2[n,p] = sum_d Wo[n,1024+d] * protos[p,d]  (f32) -> WoB[n, 1024+p] bf16; zero pad cols
__global__ __launch_bounds__(256) void k_p2(const float* __restrict__ Wo,
                                            const float* __restrict__ protos,
                                            u16* __restrict__ WoB) {
  __shared__ float swo[1024];
  int n = blockIdx.x, tid = threadIdx.x;
  ((float4*)swo)[tid] = ((const float4*)(Wo + (size_t)n * 2048 + 1024))[tid];
  __syncthreads();
  int w = tid >> 6, lane = tid & 63;
#pragma unroll
  for (int q = 0; q < 8; ++q) {
    int p = w * 8 + q;
    const float* pr = protos + (size_t)p * 1024 + lane * 16;
    const float* wv = swo + lane * 16;
    float d = 0.f;
#pragma unroll
    for (int j = 0; j < 16; ++j) d += wv[j] * pr[j];
#pragma unroll
    for (int off = 32; off; off >>= 1) d += __shfl_xor(d, off);
    if (lane == 0) WoB[(size_t)n * 1088 + 1024 + p] = f2bf(d);
  }
  if (tid < 32) WoB[(size_t)n * 1088 + 1056 + tid] = 0;
}

// ---------------- 256x256 bf16 GEMM (B^T layout), T2 swizzle, merged sync ----------------
// C[m,n] = sum_k A'[m,k] * Bm[n,k], A' = [A (lda 1024) | Aext (stride 64, K-tile 16)].
// EPI 0: C = bf16(acc + bias[n]) -> u16*, ldc 1024
// EPI 1: C = gelu(acc + bias[n]) + bf2f(residb[m*1024+n]) -> float*, ldc 1024
#define GLL(gsrc, ldst) __builtin_amdgcn_global_load_lds((gu32*)(gsrc), (lu32*)(ldst), 16, 0, 0)

template <int EPI>
__global__ __launch_bounds__(512, 2) void k_gemmF(const u16* __restrict__ A,
                                                  const u16* __restrict__ Aext,
                                                  const u16* __restrict__ Bm, int bstride,
                                                  const float* __restrict__ bias,
                                                  const u16* __restrict__ residb,
                                                  void* __restrict__ Cout,
                                                  int NT, int nbn) {
  __shared__ u16 Als[2][256 * 64];
  __shared__ u16 Bls[2][256 * 64];
  const int tid = threadIdx.x;
  const int wid = tid >> 6, lane = tid & 63;
  const int wm = wid >> 2, wn = wid & 3;
  const int lm = lane & 15, lk = lane >> 4;

  const int scol_sw = (((lane & 7) ^ ((lane >> 3) & 7)) << 3);
  const int srow = lane >> 3;

  // XCD chunked swizzle (nwg % 8 == 0)
  int g = blockIdx.x;
  int cpx = gridDim.x >> 3;
  int lin = (g & 7) * cpx + (g >> 3);
  int bn = lin % nbn, bm = lin / nbn;
  const size_t bmBase = (size_t)bm * 256;
  const size_t bnBase = (size_t)bn * 256;

  f32x4 acc[8][4];
#pragma unroll
  for (int i = 0; i < 8; ++i)
#pragma unroll
    for (int j = 0; j < 4; ++j) acc[i][j] = (f32x4){0.f, 0.f, 0.f, 0.f};

  bf16x8 a[4][2], b0[2][2], b1[2][2];

#define STAGE_A(bufv, kt, mh) do {                                              \
    int arow = (mh) * 64 + wid * 8 + srow;                                      \
    const u16 *ap0, *ap1;                                                       \
    if ((kt) < 16) {                                                            \
      ap0 = A + (bmBase + arow) * (size_t)1024 + scol_sw + (kt) * 64;           \
      ap1 = A + (bmBase + 128 + arow) * (size_t)1024 + scol_sw + (kt) * 64;     \
    } else {                                                                    \
      ap0 = Aext + (bmBase + arow) * (size_t)64 + scol_sw;                      \
      ap1 = Aext + (bmBase + 128 + arow) * (size_t)64 + scol_sw;                \
    }                                                                           \
    GLL(ap0, &Als[bufv][((mh) * 64 + wid * 8) * 64]);                           \
    GLL(ap1, &Als[bufv][(128 + (mh) * 64 + wid * 8) * 64]);                     \
  } while (0)

#define STAGE_B(bufv, kt, nh) do {                                              \
    int br0 = ((wid >> 2) << 6) + (nh) * 32 + ((wid & 3) << 3);                 \
    int bcol = scol_sw + (kt) * 64;                                             \
    GLL(Bm + (bnBase + br0 + srow) * (size_t)bstride + bcol, &Bls[bufv][br0 * 64]); \
    GLL(Bm + (bnBase + 128 + br0 + srow) * (size_t)bstride + bcol, &Bls[bufv][(128 + br0) * 64]); \
  } while (0)

#define LOAD_A(bufv, mh) do {                                                   \
    _Pragma("unroll") for (int mi2 = 0; mi2 < 4; ++mi2) {                       \
      int row = wm * 128 + (mh) * 64 + mi2 * 16 + lm;                           \
      _Pragma("unroll") for (int kk = 0; kk < 2; ++kk)                          \
        a[mi2][kk] = *(const bf16x8*)&Als[bufv][row * 64 + ((kk * 32 + lk * 8) ^ ((lm & 7) << 3))]; \
    }                                                                           \
  } while (0)

#define LOAD_B(dst, bufv, nh) do {                                              \
    _Pragma("unroll") for (int ni2 = 0; ni2 < 2; ++ni2) {                       \
      int row = wn * 64 + (nh) * 32 + ni2 * 16 + lm;                            \
      _Pragma("unroll") for (int kk = 0; kk < 2; ++kk)                          \
        dst[ni2][kk] = *(const bf16x8*)&Bls[bufv][row * 64 + ((kk * 32 + lk * 8) ^ ((lm & 7) << 3))]; \
    }                                                                           \
  } while (0)

#define BARRIER do { __builtin_amdgcn_s_barrier(); asm volatile("" ::: "memory"); } while (0)

#define MFMA_Q(bb, mh, nh) do {                                                 \
    __builtin_amdgcn_s_setprio(1);                                              \
    _Pragma("unroll") for (int mi2 = 0; mi2 < 4; ++mi2)                         \
    _Pragma("unroll") for (int ni2 = 0; ni2 < 2; ++ni2)                         \
    _Pragma("unroll") for (int kk = 0; kk < 2; ++kk)                            \
      acc[(mh) * 4 + mi2][(nh) * 2 + ni2] = __builtin_amdgcn_mfma_f32_16x16x32_bf16( \
          a[mi2][kk], bb[ni2][kk], acc[(mh) * 4 + mi2][(nh) * 2 + ni2], 0, 0, 0); \
    __builtin_amdgcn_s_setprio(0);                                              \
  } while (0)

#define TILE(T, P) do {                                                         \
    asm volatile("s_waitcnt vmcnt(0)" ::: "memory");                            \
    BARRIER;                                                                    \
    if ((T) + 1 < NT) {                                                         \
      STAGE_A((P) ^ 1, (T) + 1, 0); STAGE_B((P) ^ 1, (T) + 1, 0);               \
      STAGE_A((P) ^ 1, (T) + 1, 1); STAGE_B((P) ^ 1, (T) + 1, 1);               \
    }                                                                           \
    LOAD_A(P, 0); LOAD_B(b0, P, 0);                                             \
    MFMA_Q(b0, 0, 0);                                                           \
    LOAD_B(b1, P, 1);                                                           \
    MFMA_Q(b1, 0, 1);                                                           \
    LOAD_A(P, 1);                                                               \
    MFMA_Q(b1, 1, 1);                                                           \
    MFMA_Q(b0, 1, 0);                                                           \
  } while (0)

  // prologue: stage tile0 into buf0
  STAGE_A(0, 0, 0); STAGE_B(0, 0, 0); STAGE_A(0, 0, 1); STAGE_B(0, 0, 1);

  int T = 0;
  for (; T + 1 < NT; T += 2) {
    TILE(T, 0);
    TILE(T + 1, 1);
  }
  if (T < NT) TILE(T, 0);  // odd NT tail (parity: T even)

  // epilogue: C/D layout col = lane&15 (n), row = (lane>>4)*4 + r (m)
  const int rbase = lk * 4;
  const size_t gr0 = bmBase + wm * 128;
  const int gc0 = (int)bnBase + wn * 64;
#pragma unroll
  for (int mi = 0; mi < 8; ++mi) {
#pragma unroll
    for (int ni = 0; ni < 4; ++ni) {
      int gcol = gc0 + ni * 16 + lm;
      float bv = bias[gcol];
#pragma unroll
      for (int r = 0; r < 4; ++r) {
        size_t grow = gr0 + mi * 16 + rbase + r;
        float v = acc[mi][ni][r] + bv;
        if (EPI == 0) {
          ((u16*)Cout)[grow * 1024 + gcol] = f2bf(v);
        } else {
          float gl = 0.5f * v * (1.0f + erff(v * 0.70710678118654752f));
          float y = gl + bf2f(residb[grow * 1024 + gcol]);
          ((float*)Cout)[grow * 1024 + gcol] = y;
        }
      }
    }
  }
#undef STAGE_A
#undef STAGE_B
#undef LOAD_A
#undef LOAD_B
#undef MFMA_Q
#undef TILE
#undef BARRIER
}

// ---------------- fused: sim (MFMA) -> softmax -> attn [B,64] (cols 32..63 = 0) -------
__global__ __launch_bounds__(256) void k_mid2(const u16* __restrict__ h,
                                              const u16* __restrict__ pb,
                                              u16* __restrict__ ab) {
  __shared__ u16 attn_sm[4][16 * 32];
  const int tid = threadIdx.x;
  const int w = tid >> 6, lane = tid & 63;
  const int lm = lane & 15, lk = lane >> 4;
  const int row0 = blockIdx.x * 64 + w * 16;

  f32x4 zero = {0.f, 0.f, 0.f, 0.f};
  f32x4 acc0 = zero, acc1 = zero;
  float ss = 0.f;

  const u16* hrow = h + ((size_t)(row0 + lm) << 10) + lk * 8;
  const u16* pb0 = pb + (size_t)lm * DD + lk * 8;
  const u16* pb1 = pb + (size_t)(16 + lm) * DD + lk * 8;
#pragma unroll 4
  for (int k0 = 0; k0 < DD; k0 += 32) {
    bf16x8 af = *(const bf16x8*)(hrow + k0);
    bf16x8 b0 = *(const bf16x8*)(pb0 + k0);
    bf16x8 b1 = *(const bf16x8*)(pb1 + k0);
    acc0 = __builtin_amdgcn_mfma_f32_16x16x32_bf16(af, b0, acc0, 0, 0, 0);
    acc1 = __builtin_amdgcn_mfma_f32_16x16x32_bf16(af, b1, acc1, 0, 0, 0);
#pragma unroll
    for (int j = 0; j < 8; ++j) {
      float hv = bf2f((u16)af[j]);
      ss += hv * hv;
    }
  }
  ss += __shfl_xor(ss, 16);
  ss += __shfl_xor(ss, 32);
  float inv = 10.0f / fmaxf(sqrtf(ss), 1e-12f);

  float a0[4], a1[4];
#pragma unroll
  for (int r = 0; r < 4; ++r) {
    float invr = __shfl(inv, lk * 4 + r);
    float s0 = acc0[r] * invr;
    float s1 = acc1[r] * invr;
    float mr = fmaxf(s0, s1);
#pragma unroll
    for (int off = 1; off < 16; off <<= 1) mr = fmaxf(mr, __shfl_xor(mr, off));
    float e0 = expf(s0 - mr);
    float e1 = expf(s1 - mr);
    float sum = e0 + e1;
#pragma unroll
    for (int off = 1; off < 16; off <<= 1) sum += __shfl_xor(sum, off);
    float rs = 1.0f / sum;
    a0[r] = e0 * rs;
    a1[r] = e1 * rs;
  }

  u16* as = attn_sm[w];
#pragma unroll
  for (int r = 0; r < 4; ++r) {
    as[(lk * 4 + r) * 32 + lm] = f2bf(a0[r]);
    as[(lk * 4 + r) * 32 + 16 + lm] = f2bf(a1[r]);
  }
  __syncthreads();
  // write attn rows + zero pad: lane l -> row l>>2, 8-u16 chunk (l&3)
  int rr = lane >> 2, c8 = (lane & 3) << 3;
  int4 v = *(const int4*)(as + rr * 32 + c8);
  size_t orow = (size_t)(row0 + rr) * 64;
  *(int4*)(ab + orow + c8) = v;
  int4 z = {0, 0, 0, 0};
  *(int4*)(ab + orow + 32 + c8) = z;
}

// ---------------- in-place LayerNorm over rows of 1024 ----------------
__global__ __launch_bounds__(256) void k_ln(float* __restrict__ io,
                                            const float* __restrict__ gamma,
                                            const float* __restrict__ beta) {
  __shared__ float sb[8];
  size_t row = blockIdx.x;
  float4* rp = (float4*)(io + (row << 10));
  int tid = threadIdx.x;
  float4 v = rp[tid];
  float s = v.x + v.y + v.z + v.w;
  float q = v.x * v.x + v.y * v.y + v.z * v.z + v.w * v.w;
#pragma unroll
  for (int off = 32; off; off >>= 1) { s += __shfl_xor(s, off); q += __shfl_xor(q, off); }
  if ((tid & 63) == 0) { sb[tid >> 6] = s; sb[4 + (tid >> 6)] = q; }
  __syncthreads();
  s = sb[0] + sb[1] + sb[2] + sb[3];
  q = sb[4] + sb[5] + sb[6] + sb[7];
  float mu = s * (1.f / 1024.f);
  float var = q * (1.f / 1024.f) - mu * mu;
  float rstd = rsqrtf(var + 1e-5f);
  float4 g = ((const float4*)gamma)[tid];
  float4 b = ((const float4*)beta)[tid];
  v.x = (v.x - mu) * rstd * g.x + b.x;
  v.y = (v.y - mu) * rstd * g.y + b.y;
  v.z = (v.z - mu) * rstd * g.z + b.z;
  v.w = (v.w - mu) * rstd * g.w + b.w;
  rp[tid] = v;
}

extern "C" void kernel_launch(void* const* d_in, const int* in_sizes, int n_in,
                              void* d_out, int out_size, void* d_ws, size_t ws_size,
                              hipStream_t stream) {
  const float* x      = (const float*)d_in[0];
  const float* Wi     = (const float*)d_in[1];
  const float* bi     = (const float*)d_in[2];
  const float* Wo     = (const float*)d_in[3];
  const float* bo     = (const float*)d_in[4];
  const float* gamma  = (const float*)d_in[5];
  const float* beta   = (const float*)d_in[6];
  const float* protos = (const float*)d_in[7];
  const int Brows = in_sizes[0] / DD;  // 65536

  u16* xb   = (u16*)d_ws;                        // [B, 1024] bf16
  u16* WiB  = xb + (size_t)Brows * 1024;         // [1024, 1024]
  u16* WoB  = WiB + (size_t)1024 * 1024;         // [1024, 1088]  (Wo1 | P2 | pad)
  u16* pb   = WoB + (size_t)1024 * 1088;         // [32, 1024] normalized
  u16* ab   = pb + (size_t)PP * DD;              // [B, 64] attn (cols 32..63 zero)
  u16* hbuf = (u16*)d_out;                       // h bf16 lives in d_out storage

  k_convert<<<4096, 256, 0, stream>>>(x, xb, Brows * 256);
  k_convert<<<1024, 256, 0, stream>>>(Wi, WiB, 1024 * 1024 / 4);
  k_convert_wo<<<1024, 256, 0, stream>>>(Wo, WoB);
  k_proto_prep<<<PP, 256, 0, stream>>>(protos, pb);
  k_p2<<<1024, 256, 0, stream>>>(Wo, protos, WoB);

  const int nbn = 1024 / 256;                    // 4 col-blocks
  const int nwg = nbn * (Brows / 256);           // 1024 blocks (mod 8 == 0)

  // h = x @ Wi^T + bi   (K = 1024, 16 tiles)
  k_gemmF<0><<<nwg, 512, 0, stream>>>(xb, nullptr, WiB, 1024, bi, nullptr,
                                      (void*)hbuf, 16, nbn);
  // sim -> softmax -> attn
  k_mid2<<<Brows / 64, 256, 0, stream>>>(hbuf, pb, ab);
  // y = gelu(x @ Wo1^T + attn @ P2 + bo) + bf16(x)  (K = 1088, 17 tiles)
  k_gemmF<1><<<nwg, 512, 0, stream>>>(xb, ab, WoB, 1088, bo, xb,
                                      d_out, 17, nbn);
  // in-place LayerNorm
  k_ln<<<Brows, 256, 0, stream>>>((float*)d_out, gamma, beta);
}

// Round 12
// 583.345 us; speedup vs baseline: 1.6953x; 1.2475x over previous
//
#include <hip/hip_runtime.h>
#include <hip/hip_bf16.h>
#include <math.h>

typedef unsigned short u16;
typedef __attribute__((ext_vector_type(8))) short bf16x8;
typedef __attribute__((ext_vector_type(4))) float f32x4;
typedef __attribute__((address_space(1))) unsigned int gu32;
typedef __attribute__((address_space(3))) unsigned int lu32;

#define DD 1024
#define PP 32

__device__ __forceinline__ u16 f2bf(float f) {
  unsigned u = __float_as_uint(f);
  unsigned r = u + 0x7fffu + ((u >> 16) & 1u);
  return (u16)(r >> 16);
}
__device__ __forceinline__ float bf2f(u16 h) {
  return __uint_as_float(((unsigned)h) << 16);
}

// tanh-GELU: 0.5 v (1 + tanh(0.7978845608 (v + 0.044715 v^3))); tanh via exp2+rcp.
__device__ __forceinline__ float gelu_t(float v) {
  float u = v + 0.044715f * v * v * v;
  float p = __builtin_amdgcn_exp2f(2.302590614f * u);  // e^{2*0.79788456*u}
  float th = 1.0f - 2.0f * __builtin_amdgcn_rcpf(p + 1.0f);
  return 0.5f * v * (1.0f + th);
}

// ---------------- conversions ----------------
__global__ __launch_bounds__(256) void k_convert(const float* __restrict__ in,
                                                 u16* __restrict__ out, int n4) {
  for (int i = blockIdx.x * 256 + threadIdx.x; i < n4; i += gridDim.x * 256) {
    float4 v = ((const float4*)in)[i];
    ushort4 o;
    o.x = f2bf(v.x); o.y = f2bf(v.y); o.z = f2bf(v.z); o.w = f2bf(v.w);
    ((ushort4*)out)[i] = o;
  }
}

// Wo [1024,2048] f32 -> WoB[n, 0:1024] bf16 (stride 1088)
__global__ __launch_bounds__(256) void k_convert_wo(const float* __restrict__ Wo,
                                                    u16* __restrict__ WoB) {
  int i = blockIdx.x * 256 + threadIdx.x;  // 1024*256
  int n = i >> 8, c4 = i & 255;
  float4 v = ((const float4*)(Wo + (size_t)n * 2048))[c4];
  ushort4 o;
  o.x = f2bf(v.x); o.y = f2bf(v.y); o.z = f2bf(v.z); o.w = f2bf(v.w);
  *(ushort4*)(WoB + (size_t)n * 1088 + c4 * 4) = o;
}

// prototypes [32,1024] f32 -> row-l2-normalized bf16 (for sim)
__global__ __launch_bounds__(256) void k_proto_prep(const float* __restrict__ protos,
                                                    u16* __restrict__ pb) {
  __shared__ float sb[4];
  int row = blockIdx.x, tid = threadIdx.x;
  float4 v = ((const float4*)(protos + row * DD))[tid];
  float q = v.x * v.x + v.y * v.y + v.z * v.z + v.w * v.w;
#pragma unroll
  for (int off = 32; off; off >>= 1) q += __shfl_xor(q, off);
  if ((tid & 63) == 0) sb[tid >> 6] = q;
  __syncthreads();
  q = sb[0] + sb[1] + sb[2] + sb[3];
  float inv = 1.0f / fmaxf(sqrtf(q), 1e-12f);
  ushort4 o;
  o.x = f2bf(v.x * inv); o.y = f2bf(v.y * inv); o.z = f2bf(v.z * inv); o.w = f2bf(v.w * inv);
  ((ushort4*)(pb + row * DD))[tid] = o;
}

// P2[n,p] = sum_d Wo[n,1024+d] * protos[p,d]  (f32) -> WoB[n, 1024+p] bf16; zero pad cols
__global__ __launch_bounds__(256) void k_p2(const float* __restrict__ Wo,
                                            const float* __restrict__ protos,
                                            u16* __restrict__ WoB) {
  __shared__ float swo[1024];
  int n = blockIdx.x, tid = threadIdx.x;
  ((float4*)swo)[tid] = ((const float4*)(Wo + (size_t)n * 2048 + 1024))[tid];
  __syncthreads();
  int w = tid >> 6, lane = tid & 63;
#pragma unroll
  for (int q = 0; q < 8; ++q) {
    int p = w * 8 + q;
    const float* pr = protos + (size_t)p * 1024 + lane * 16;
    const float* wv = swo + lane * 16;
    float d = 0.f;
#pragma unroll
    for (int j = 0; j < 16; ++j) d += wv[j] * pr[j];
#pragma unroll
    for (int off = 32; off; off >>= 1) d += __shfl_xor(d, off);
    if (lane == 0) WoB[(size_t)n * 1088 + 1024 + p] = f2bf(d);
  }
  if (tid < 32) WoB[(size_t)n * 1088 + 1056 + tid] = 0;
}

// ---------------- 256x256 bf16 GEMM (B^T layout), T2 swizzle, merged sync ----------------
// C[m,n] = sum_k A'[m,k] * Bm[n,k], A' = [A (lda 1024) | Aext (stride 64, K-tile 16)].
// EPI 0: C = bf16(acc + bias[n]) -> u16*, u16-stride 1024  (h)
// EPI 1: C = bf16(gelu(acc+bias[n]) + bf2f(residb[m*1024+n])) -> u16*, u16-stride 2048
//        (y bf16 packed into the low half of each f32 out-row slot)
#define GLL(gsrc, ldst) __builtin_amdgcn_global_load_lds((gu32*)(gsrc), (lu32*)(ldst), 16, 0, 0)

template <int EPI, int NT>
__global__ __launch_bounds__(512, 2) void k_gemmF(const u16* __restrict__ A,
                                                  const u16* __restrict__ Aext,
                                                  const u16* __restrict__ Bm, int bstride,
                                                  const float* __restrict__ bias,
                                                  const u16* __restrict__ residb,
                                                  u16* __restrict__ Cout,
                                                  int nbn) {
  __shared__ u16 Als[2][256 * 64];
  __shared__ u16 Bls[2][256 * 64];
  const int tid = threadIdx.x;
  const int wid = tid >> 6, lane = tid & 63;
  const int wm = wid >> 2, wn = wid & 3;
  const int lm = lane & 15, lk = lane >> 4;

  const int scol_sw = (((lane & 7) ^ ((lane >> 3) & 7)) << 3);
  const int srow = lane >> 3;

  // XCD chunked swizzle (nwg % 8 == 0)
  int g = blockIdx.x;
  int cpx = gridDim.x >> 3;
  int lin = (g & 7) * cpx + (g >> 3);
  int bn = lin % nbn, bm = lin / nbn;
  const size_t bmBase = (size_t)bm * 256;
  const size_t bnBase = (size_t)bn * 256;

  f32x4 acc[8][4];
#pragma unroll
  for (int i = 0; i < 8; ++i)
#pragma unroll
    for (int j = 0; j < 4; ++j) acc[i][j] = (f32x4){0.f, 0.f, 0.f, 0.f};

  bf16x8 a[4][2], b0[2][2], b1[2][2];

#define STAGE_A(bufv, kt, mh) do {                                              \
    int arow = (mh) * 64 + wid * 8 + srow;                                      \
    const u16 *ap0, *ap1;                                                       \
    if ((kt) < 16) {                                                            \
      ap0 = A + (bmBase + arow) * (size_t)1024 + scol_sw + (kt) * 64;           \
      ap1 = A + (bmBase + 128 + arow) * (size_t)1024 + scol_sw + (kt) * 64;     \
    } else {                                                                    \
      ap0 = Aext + (bmBase + arow) * (size_t)64 + scol_sw;                      \
      ap1 = Aext + (bmBase + 128 + arow) * (size_t)64 + scol_sw;                \
    }                                                                           \
    GLL(ap0, &Als[bufv][((mh) * 64 + wid * 8) * 64]);                           \
    GLL(ap1, &Als[bufv][(128 + (mh) * 64 + wid * 8) * 64]);                     \
  } while (0)

#define STAGE_B(bufv, kt, nh) do {                                              \
    int br0 = ((wid >> 2) << 6) + (nh) * 32 + ((wid & 3) << 3);                 \
    int bcol = scol_sw + (kt) * 64;                                             \
    GLL(Bm + (bnBase + br0 + srow) * (size_t)bstride + bcol, &Bls[bufv][br0 * 64]); \
    GLL(Bm + (bnBase + 128 + br0 + srow) * (size_t)bstride + bcol, &Bls[bufv][(128 + br0) * 64]); \
  } while (0)

#define LOAD_A(bufv, mh) do {                                                   \
    _Pragma("unroll") for (int mi2 = 0; mi2 < 4; ++mi2) {                       \
      int row = wm * 128 + (mh) * 64 + mi2 * 16 + lm;                           \
      _Pragma("unroll") for (int kk = 0; kk < 2; ++kk)                          \
        a[mi2][kk] = *(const bf16x8*)&Als[bufv][row * 64 + ((kk * 32 + lk * 8) ^ ((lm & 7) << 3))]; \
    }                                                                           \
  } while (0)

#define LOAD_B(dst, bufv, nh) do {                                              \
    _Pragma("unroll") for (int ni2 = 0; ni2 < 2; ++ni2) {                       \
      int row = wn * 64 + (nh) * 32 + ni2 * 16 + lm;                            \
      _Pragma("unroll") for (int kk = 0; kk < 2; ++kk)                          \
        dst[ni2][kk] = *(const bf16x8*)&Bls[bufv][row * 64 + ((kk * 32 + lk * 8) ^ ((lm & 7) << 3))]; \
    }                                                                           \
  } while (0)

#define BARRIER do { __builtin_amdgcn_s_barrier(); asm volatile("" ::: "memory"); } while (0)

#define MFMA_Q(bb, mh, nh) do {                                                 \
    __builtin_amdgcn_s_setprio(1);                                              \
    _Pragma("unroll") for (int mi2 = 0; mi2 < 4; ++mi2)                         \
    _Pragma("unroll") for (int ni2 = 0; ni2 < 2; ++ni2)                         \
    _Pragma("unroll") for (int kk = 0; kk < 2; ++kk)                            \
      acc[(mh) * 4 + mi2][(nh) * 2 + ni2] = __builtin_amdgcn_mfma_f32_16x16x32_bf16( \
          a[mi2][kk], bb[ni2][kk], acc[(mh) * 4 + mi2][(nh) * 2 + ni2], 0, 0, 0); \
    __builtin_amdgcn_s_setprio(0);                                              \
  } while (0)

#define TILE(T, P) do {                                                         \
    asm volatile("s_waitcnt vmcnt(0)" ::: "memory");                            \
    BARRIER;                                                                    \
    if ((T) + 1 < NT) {                                                         \
      STAGE_A((P) ^ 1, (T) + 1, 0); STAGE_B((P) ^ 1, (T) + 1, 0);               \
      STAGE_A((P) ^ 1, (T) + 1, 1); STAGE_B((P) ^ 1, (T) + 1, 1);               \
    }                                                                           \
    LOAD_A(P, 0); LOAD_B(b0, P, 0);                                             \
    MFMA_Q(b0, 0, 0);                                                           \
    LOAD_B(b1, P, 1);                                                           \
    MFMA_Q(b1, 0, 1);                                                           \
    LOAD_A(P, 1);                                                               \
    MFMA_Q(b1, 1, 1);                                                           \
    MFMA_Q(b0, 1, 0);                                                           \
  } while (0)

  // prologue: stage tile0 into buf0
  STAGE_A(0, 0, 0); STAGE_B(0, 0, 0); STAGE_A(0, 0, 1); STAGE_B(0, 0, 1);

#pragma unroll
  for (int T = 0; T + 1 < NT; T += 2) {
    TILE(T, 0);
    TILE(T + 1, 1);
  }
  if (NT & 1) TILE(NT - 1, 0);  // odd NT tail (parity: NT-1 even)

  // epilogue: C/D layout col = lane&15 (n), row = (lane>>4)*4 + r (m)
  const int rbase = lk * 4;
  const size_t gr0 = bmBase + wm * 128;
  const int gc0 = (int)bnBase + wn * 64;
#pragma unroll
  for (int mi = 0; mi < 8; ++mi) {
#pragma unroll
    for (int ni = 0; ni < 4; ++ni) {
      int gcol = gc0 + ni * 16 + lm;
      float bv = bias[gcol];
#pragma unroll
      for (int r = 0; r < 4; ++r) {
        size_t grow = gr0 + mi * 16 + rbase + r;
        float v = acc[mi][ni][r] + bv;
        if (EPI == 0) {
          Cout[grow * 1024 + gcol] = f2bf(v);
        } else {
          float y = gelu_t(v) + bf2f(residb[grow * 1024 + gcol]);
          Cout[grow * 2048 + gcol] = f2bf(y);
        }
      }
    }
  }
#undef STAGE_A
#undef STAGE_B
#undef LOAD_A
#undef LOAD_B
#undef MFMA_Q
#undef TILE
#undef BARRIER
}

// ---------------- fused: sim (MFMA) -> softmax -> attn [B,64] (cols 32..63 = 0) -------
__global__ __launch_bounds__(256) void k_mid2(const u16* __restrict__ h,
                                              const u16* __restrict__ pb,
                                              u16* __restrict__ ab) {
  __shared__ u16 attn_sm[4][16 * 32];
  const int tid = threadIdx.x;
  const int w = tid >> 6, lane = tid & 63;
  const int lm = lane & 15, lk = lane >> 4;
  const int row0 = blockIdx.x * 64 + w * 16;

  f32x4 zero = {0.f, 0.f, 0.f, 0.f};
  f32x4 acc0 = zero, acc1 = zero;
  float ss = 0.f;

  const u16* hrow = h + ((size_t)(row0 + lm) << 10) + lk * 8;
  const u16* pb0 = pb + (size_t)lm * DD + lk * 8;
  const u16* pb1 = pb + (size_t)(16 + lm) * DD + lk * 8;
#pragma unroll 4
  for (int k0 = 0; k0 < DD; k0 += 32) {
    bf16x8 af = *(const bf16x8*)(hrow + k0);
    bf16x8 b0 = *(const bf16x8*)(pb0 + k0);
    bf16x8 b1 = *(const bf16x8*)(pb1 + k0);
    acc0 = __builtin_amdgcn_mfma_f32_16x16x32_bf16(af, b0, acc0, 0, 0, 0);
    acc1 = __builtin_amdgcn_mfma_f32_16x16x32_bf16(af, b1, acc1, 0, 0, 0);
#pragma unroll
    for (int j = 0; j < 8; ++j) {
      float hv = bf2f((u16)af[j]);
      ss += hv * hv;
    }
  }
  ss += __shfl_xor(ss, 16);
  ss += __shfl_xor(ss, 32);
  float inv = 10.0f / fmaxf(sqrtf(ss), 1e-12f);

  float a0[4], a1[4];
#pragma unroll
  for (int r = 0; r < 4; ++r) {
    float invr = __shfl(inv, lk * 4 + r);
    float s0 = acc0[r] * invr;
    float s1 = acc1[r] * invr;
    float mr = fmaxf(s0, s1);
#pragma unroll
    for (int off = 1; off < 16; off <<= 1) mr = fmaxf(mr, __shfl_xor(mr, off));
    float e0 = expf(s0 - mr);
    float e1 = expf(s1 - mr);
    float sum = e0 + e1;
#pragma unroll
    for (int off = 1; off < 16; off <<= 1) sum += __shfl_xor(sum, off);
    float rs = 1.0f / sum;
    a0[r] = e0 * rs;
    a1[r] = e1 * rs;
  }

  u16* as = attn_sm[w];
#pragma unroll
  for (int r = 0; r < 4; ++r) {
    as[(lk * 4 + r) * 32 + lm] = f2bf(a0[r]);
    as[(lk * 4 + r) * 32 + 16 + lm] = f2bf(a1[r]);
  }
  __syncthreads();
  // write attn rows + zero pad: lane l -> row l>>2, 8-u16 chunk (l&3)
  int rr = lane >> 2, c8 = (lane & 3) << 3;
  int4 v = *(const int4*)(as + rr * 32 + c8);
  size_t orow = (size_t)(row0 + rr) * 64;
  *(int4*)(ab + orow + c8) = v;
  int4 z = {0, 0, 0, 0};
  *(int4*)(ab + orow + 32 + c8) = z;
}

// ---------------- LayerNorm: read y bf16 (low half of each out-row slot), write f32 ----
__global__ __launch_bounds__(256) void k_ln2(u16* __restrict__ ybase,
                                             float* __restrict__ out,
                                             const float* __restrict__ gamma,
                                             const float* __restrict__ beta) {
  __shared__ float sb[8];
  size_t row = blockIdx.x;
  int tid = threadIdx.x;
  ushort4 v4 = ((const ushort4*)(ybase + row * 2048))[tid];
  float y0 = bf2f(v4.x), y1 = bf2f(v4.y), y2 = bf2f(v4.z), y3 = bf2f(v4.w);
  float s = y0 + y1 + y2 + y3;
  float q = y0 * y0 + y1 * y1 + y2 * y2 + y3 * y3;
#pragma unroll
  for (int off = 32; off; off >>= 1) { s += __shfl_xor(s, off); q += __shfl_xor(q, off); }
  if ((tid & 63) == 0) { sb[tid >> 6] = s; sb[4 + (tid >> 6)] = q; }
  __syncthreads();  // also drains all loads before any store below
  s = sb[0] + sb[1] + sb[2] + sb[3];
  q = sb[4] + sb[5] + sb[6] + sb[7];
  float mu = s * (1.f / 1024.f);
  float var = q * (1.f / 1024.f) - mu * mu;
  float rstd = rsqrtf(var + 1e-5f);
  float4 g = ((const float4*)gamma)[tid];
  float4 b = ((const float4*)beta)[tid];
  float4 o;
  o.x = (y0 - mu) * rstd * g.x + b.x;
  o.y = (y1 - mu) * rstd * g.y + b.y;
  o.z = (y2 - mu) * rstd * g.z + b.z;
  o.w = (y3 - mu) * rstd * g.w + b.w;
  ((float4*)(out + (row << 10)))[tid] = o;
}

extern "C" void kernel_launch(void* const* d_in, const int* in_sizes, int n_in,
                              void* d_out, int out_size, void* d_ws, size_t ws_size,
                              hipStream_t stream) {
  const float* x      = (const float*)d_in[0];
  const float* Wi     = (const float*)d_in[1];
  const float* bi     = (const float*)d_in[2];
  const float* Wo     = (const float*)d_in[3];
  const float* bo     = (const float*)d_in[4];
  const float* gamma  = (const float*)d_in[5];
  const float* beta   = (const float*)d_in[6];
  const float* protos = (const float*)d_in[7];
  const int Brows = in_sizes[0] / DD;  // 65536

  u16* xb   = (u16*)d_ws;                        // [B, 1024] bf16
  u16* WiB  = xb + (size_t)Brows * 1024;         // [1024, 1024]
  u16* WoB  = WiB + (size_t)1024 * 1024;         // [1024, 1088]  (Wo1 | P2 | pad)
  u16* pb   = WoB + (size_t)1024 * 1088;         // [32, 1024] normalized
  u16* ab   = pb + (size_t)PP * DD;              // [B, 64] attn (cols 32..63 zero)
  u16* hbuf = (u16*)d_out;                       // h bf16 lives in d_out storage
  u16* ybuf = (u16*)d_out;                       // y bf16, u16-stride 2048 (low half of slots)

  k_convert<<<4096, 256, 0, stream>>>(x, xb, Brows * 256);
  k_convert<<<1024, 256, 0, stream>>>(Wi, WiB, 1024 * 1024 / 4);
  k_convert_wo<<<1024, 256, 0, stream>>>(Wo, WoB);
  k_proto_prep<<<PP, 256, 0, stream>>>(protos, pb);
  k_p2<<<1024, 256, 0, stream>>>(Wo, protos, WoB);

  const int nbn = 1024 / 256;                    // 4 col-blocks
  const int nwg = nbn * (Brows / 256);           // 1024 blocks (mod 8 == 0)

  // h = x @ Wi^T + bi   (K = 1024, 16 tiles)
  k_gemmF<0, 16><<<nwg, 512, 0, stream>>>(xb, xb, WiB, 1024, bi, nullptr,
                                          hbuf, nbn);
  // sim -> softmax -> attn
  k_mid2<<<Brows / 64, 256, 0, stream>>>(hbuf, pb, ab);
  // y = bf16(gelu(x @ Wo1^T + attn @ P2 + bo) + bf16(x))  (K = 1088, 17 tiles)
  k_gemmF<1, 17><<<nwg, 512, 0, stream>>>(xb, ab, WoB, 1088, bo, xb,
                                          ybuf, nbn);
  // LayerNorm: y bf16 -> out f32 (in-slot)
  k_ln2<<<Brows, 256, 0, stream>>>(ybuf, (float*)d_out, gamma, beta);
}

// Round 13
// 524.661 us; speedup vs baseline: 1.8849x; 1.1119x over previous
//
#include <hip/hip_runtime.h>
#include <hip/hip_bf16.h>
#include <math.h>

typedef unsigned short u16;
typedef __attribute__((ext_vector_type(8))) short bf16x8;
typedef __attribute__((ext_vector_type(4))) float f32x4;
typedef __attribute__((address_space(1))) unsigned int gu32;
typedef __attribute__((address_space(3))) unsigned int lu32;

#define DD 1024
#define PP 32

__device__ __forceinline__ u16 f2bf(float f) {
  unsigned u = __float_as_uint(f);
  unsigned r = u + 0x7fffu + ((u >> 16) & 1u);
  return (u16)(r >> 16);
}
__device__ __forceinline__ float bf2f(u16 h) {
  return __uint_as_float(((unsigned)h) << 16);
}

// tanh-GELU: 0.5 v (1 + tanh(0.7978845608 (v + 0.044715 v^3))); tanh via exp2+rcp.
__device__ __forceinline__ float gelu_t(float v) {
  float u = v + 0.044715f * v * v * v;
  float p = __builtin_amdgcn_exp2f(2.302590614f * u);  // e^{2*0.79788456*u}
  float th = 1.0f - 2.0f * __builtin_amdgcn_rcpf(p + 1.0f);
  return 0.5f * v * (1.0f + th);
}

// ---------------- conversions ----------------
__global__ __launch_bounds__(256) void k_convert(const float* __restrict__ in,
                                                 u16* __restrict__ out, int n4) {
  for (int i = blockIdx.x * 256 + threadIdx.x; i < n4; i += gridDim.x * 256) {
    float4 v = ((const float4*)in)[i];
    ushort4 o;
    o.x = f2bf(v.x); o.y = f2bf(v.y); o.z = f2bf(v.z); o.w = f2bf(v.w);
    ((ushort4*)out)[i] = o;
  }
}

// Wo [1024,2048] f32 -> WoB[n, 0:1024] bf16 (stride 1088)
__global__ __launch_bounds__(256) void k_convert_wo(const float* __restrict__ Wo,
                                                    u16* __restrict__ WoB) {
  int i = blockIdx.x * 256 + threadIdx.x;  // 1024*256
  int n = i >> 8, c4 = i & 255;
  float4 v = ((const float4*)(Wo + (size_t)n * 2048))[c4];
  ushort4 o;
  o.x = f2bf(v.x); o.y = f2bf(v.y); o.z = f2bf(v.z); o.w = f2bf(v.w);
  *(ushort4*)(WoB + (size_t)n * 1088 + c4 * 4) = o;
}

// prototypes [32,1024] f32 -> row-l2-normalized bf16 (for sim)
__global__ __launch_bounds__(256) void k_proto_prep(const float* __restrict__ protos,
                                                    u16* __restrict__ pb) {
  __shared__ float sb[4];
  int row = blockIdx.x, tid = threadIdx.x;
  float4 v = ((const float4*)(protos + row * DD))[tid];
  float q = v.x * v.x + v.y * v.y + v.z * v.z + v.w * v.w;
#pragma unroll
  for (int off = 32; off; off >>= 1) q += __shfl_xor(q, off);
  if ((tid & 63) == 0) sb[tid >> 6] = q;
  __syncthreads();
  q = sb[0] + sb[1] + sb[2] + sb[3];
  float inv = 1.0f / fmaxf(sqrtf(q), 1e-12f);
  ushort4 o;
  o.x = f2bf(v.x * inv); o.y = f2bf(v.y * inv); o.z = f2bf(v.z * inv); o.w = f2bf(v.w * inv);
  ((ushort4*)(pb + row * DD))[tid] = o;
}

// P2[n,p] = sum_d Wo[n,1024+d] * protos[p,d]  (f32) -> WoB[n, 1024+p] bf16; zero pad cols
__global__ __launch_bounds__(256) void k_p2(const float* __restrict__ Wo,
                                            const float* __restrict__ protos,
                                            u16* __restrict__ WoB) {
  __shared__ float swo[1024];
  int n = blockIdx.x, tid = threadIdx.x;
  ((float4*)swo)[tid] = ((const float4*)(Wo + (size_t)n * 2048 + 1024))[tid];
  __syncthreads();
  int w = tid >> 6, lane = tid & 63;
#pragma unroll
  for (int q = 0; q < 8; ++q) {
    int p = w * 8 + q;
    const float* pr = protos + (size_t)p * 1024 + lane * 16;
    const float* wv = swo + lane * 16;
    float d = 0.f;
#pragma unroll
    for (int j = 0; j < 16; ++j) d += wv[j] * pr[j];
#pragma unroll
    for (int off = 32; off; off >>= 1) d += __shfl_xor(d, off);
    if (lane == 0) WoB[(size_t)n * 1088 + 1024 + p] = f2bf(d);
  }
  if (tid < 32) WoB[(size_t)n * 1088 + 1056 + tid] = 0;
}

// ---------------- 256x256 bf16 GEMM (B^T layout), T2 swizzle, merged sync ----------------
// C[m,n] = sum_k A'[m,k] * Bm[n,k], A' = [A (lda 1024) | Aext (stride 64, K-tile 16)].
// EPI 0: C = bf16(acc + bias[n]) -> u16*, u16-stride 1024  (h)
// EPI 1: C = bf16(gelu(acc+bias[n]) + bf2f(residb[m*1024+n])) -> u16*, u16-stride 2048
// Epilogue goes through an in-LDS transpose (per-wave 64x72-u16 chunks) so all global
// stores (and the EPI1 residual loads) are coalesced 16B accesses.
#define GLL(gsrc, ldst) __builtin_amdgcn_global_load_lds((gu32*)(gsrc), (lu32*)(ldst), 16, 0, 0)

template <int EPI, int NT>
__global__ __launch_bounds__(512, 2) void k_gemmF(const u16* __restrict__ A,
                                                  const u16* __restrict__ Aext,
                                                  const u16* __restrict__ Bm, int bstride,
                                                  const float* __restrict__ bias,
                                                  const u16* __restrict__ residb,
                                                  u16* __restrict__ Cout,
                                                  int nbn) {
  __shared__ u16 Lsh[65536];  // [A dbuf 32768 | B dbuf 32768]
#define ALS(bufv, idx) (Lsh + (bufv) * 16384 + (idx))
#define BLS(bufv, idx) (Lsh + 32768 + (bufv) * 16384 + (idx))
  const int tid = threadIdx.x;
  const int wid = tid >> 6, lane = tid & 63;
  const int wm = wid >> 2, wn = wid & 3;
  const int lm = lane & 15, lk = lane >> 4;

  const int scol_sw = (((lane & 7) ^ ((lane >> 3) & 7)) << 3);
  const int srow = lane >> 3;

  // XCD chunked swizzle (nwg % 8 == 0)
  int g = blockIdx.x;
  int cpx = gridDim.x >> 3;
  int lin = (g & 7) * cpx + (g >> 3);
  int bn = lin % nbn, bm = lin / nbn;
  const size_t bmBase = (size_t)bm * 256;
  const size_t bnBase = (size_t)bn * 256;

  f32x4 acc[8][4];
#pragma unroll
  for (int i = 0; i < 8; ++i)
#pragma unroll
    for (int j = 0; j < 4; ++j) acc[i][j] = (f32x4){0.f, 0.f, 0.f, 0.f};

  bf16x8 a[4][2], b0[2][2], b1[2][2];

#define STAGE_A(bufv, kt, mh) do {                                              \
    int arow = (mh) * 64 + wid * 8 + srow;                                      \
    const u16 *ap0, *ap1;                                                       \
    if ((kt) < 16) {                                                            \
      ap0 = A + (bmBase + arow) * (size_t)1024 + scol_sw + (kt) * 64;           \
      ap1 = A + (bmBase + 128 + arow) * (size_t)1024 + scol_sw + (kt) * 64;     \
    } else {                                                                    \
      ap0 = Aext + (bmBase + arow) * (size_t)64 + scol_sw;                      \
      ap1 = Aext + (bmBase + 128 + arow) * (size_t)64 + scol_sw;                \
    }                                                                           \
    GLL(ap0, ALS(bufv, ((mh) * 64 + wid * 8) * 64));                            \
    GLL(ap1, ALS(bufv, (128 + (mh) * 64 + wid * 8) * 64));                      \
  } while (0)

#define STAGE_B(bufv, kt, nh) do {                                              \
    int br0 = ((wid >> 2) << 6) + (nh) * 32 + ((wid & 3) << 3);                 \
    int bcol = scol_sw + (kt) * 64;                                             \
    GLL(Bm + (bnBase + br0 + srow) * (size_t)bstride + bcol, BLS(bufv, br0 * 64)); \
    GLL(Bm + (bnBase + 128 + br0 + srow) * (size_t)bstride + bcol, BLS(bufv, (128 + br0) * 64)); \
  } while (0)

#define LOAD_A(bufv, mh) do {                                                   \
    _Pragma("unroll") for (int mi2 = 0; mi2 < 4; ++mi2) {                       \
      int row = wm * 128 + (mh) * 64 + mi2 * 16 + lm;                           \
      _Pragma("unroll") for (int kk = 0; kk < 2; ++kk)                          \
        a[mi2][kk] = *(const bf16x8*)ALS(bufv, row * 64 + ((kk * 32 + lk * 8) ^ ((lm & 7) << 3))); \
    }                                                                           \
  } while (0)

#define LOAD_B(dst, bufv, nh) do {                                              \
    _Pragma("unroll") for (int ni2 = 0; ni2 < 2; ++ni2) {                       \
      int row = wn * 64 + (nh) * 32 + ni2 * 16 + lm;                            \
      _Pragma("unroll") for (int kk = 0; kk < 2; ++kk)                          \
        dst[ni2][kk] = *(const bf16x8*)BLS(bufv, row * 64 + ((kk * 32 + lk * 8) ^ ((lm & 7) << 3))); \
    }                                                                           \
  } while (0)

#define BARRIER do { __builtin_amdgcn_s_barrier(); asm volatile("" ::: "memory"); } while (0)

#define MFMA_Q(bb, mh, nh) do {                                                 \
    __builtin_amdgcn_s_setprio(1);                                              \
    _Pragma("unroll") for (int mi2 = 0; mi2 < 4; ++mi2)                         \
    _Pragma("unroll") for (int ni2 = 0; ni2 < 2; ++ni2)                         \
    _Pragma("unroll") for (int kk = 0; kk < 2; ++kk)                            \
      acc[(mh) * 4 + mi2][(nh) * 2 + ni2] = __builtin_amdgcn_mfma_f32_16x16x32_bf16( \
          a[mi2][kk], bb[ni2][kk], acc[(mh) * 4 + mi2][(nh) * 2 + ni2], 0, 0, 0); \
    __builtin_amdgcn_s_setprio(0);                                              \
  } while (0)

#define TILE(T, P) do {                                                         \
    asm volatile("s_waitcnt vmcnt(0)" ::: "memory");                            \
    BARRIER;                                                                    \
    if ((T) + 1 < NT) {                                                         \
      STAGE_A((P) ^ 1, (T) + 1, 0); STAGE_B((P) ^ 1, (T) + 1, 0);               \
      STAGE_A((P) ^ 1, (T) + 1, 1); STAGE_B((P) ^ 1, (T) + 1, 1);               \
    }                                                                           \
    LOAD_A(P, 0); LOAD_B(b0, P, 0);                                             \
    MFMA_Q(b0, 0, 0);                                                           \
    LOAD_B(b1, P, 1);                                                           \
    MFMA_Q(b1, 0, 1);                                                           \
    LOAD_A(P, 1);                                                               \
    MFMA_Q(b1, 1, 1);                                                           \
    MFMA_Q(b0, 1, 0);                                                           \
  } while (0)

  // prologue: stage tile0 into buf0
  STAGE_A(0, 0, 0); STAGE_B(0, 0, 0); STAGE_A(0, 0, 1); STAGE_B(0, 0, 1);

#pragma unroll
  for (int T = 0; T + 1 < NT; T += 2) {
    TILE(T, 0);
    TILE(T + 1, 1);
  }
  if (NT & 1) TILE(NT - 1, 0);  // odd NT tail (parity: NT-1 even)

  // ---- epilogue: in-LDS transpose -> coalesced 16B stores (and resid loads) ----
  __syncthreads();  // all waves done reading the K-loop tiles
  u16* eb = Lsh + wid * 4608;  // per-wave 64 x 72 u16 (stride 144B: 16B-aligned rows)
  const size_t gr0 = bmBase + wm * 128;
  const int gc0 = (int)bnBase + wn * 64;
#pragma unroll
  for (int ch = 0; ch < 2; ++ch) {
    // scatter acc (bf16, bias/gelu applied) into the per-wave transpose buffer
#pragma unroll
    for (int mi2 = 0; mi2 < 4; ++mi2) {
      int mi = ch * 4 + mi2;
#pragma unroll
      for (int ni = 0; ni < 4; ++ni) {
        int col = ni * 16 + lm;
        float bv = bias[gc0 + ni * 16 + lm];
#pragma unroll
        for (int r = 0; r < 4; ++r) {
          int rowL = mi2 * 16 + lk * 4 + r;
          float v = acc[mi][ni][r] + bv;
          if (EPI == 1) v = gelu_t(v);
          eb[rowL * 72 + (col ^ (((rowL >> 2) & 3) << 3))] = f2bf(v);
        }
      }
    }
    // coalesced flush: 8 iters x (8 rows x 64 cols), ushort8 stores
#pragma unroll
    for (int i = 0; i < 8; ++i) {
      int rowL = i * 8 + (lane >> 3);
      int c8 = (lane & 7) * 8;
      bf16x8 yv = *(const bf16x8*)&eb[rowL * 72 + (c8 ^ (((rowL >> 2) & 3) << 3))];
      size_t grow = gr0 + ch * 64 + rowL;
      if (EPI == 0) {
        *(bf16x8*)(Cout + grow * 1024 + gc0 + c8) = yv;
      } else {
        bf16x8 rv = *(const bf16x8*)(residb + grow * 1024 + gc0 + c8);
        bf16x8 ov;
#pragma unroll
        for (int j = 0; j < 8; ++j)
          ov[j] = (short)f2bf(bf2f((u16)yv[j]) + bf2f((u16)rv[j]));
        *(bf16x8*)(Cout + grow * 2048 + gc0 + c8) = ov;
      }
    }
  }
#undef STAGE_A
#undef STAGE_B
#undef LOAD_A
#undef LOAD_B
#undef MFMA_Q
#undef TILE
#undef BARRIER
#undef ALS
#undef BLS
}

// ---------------- fused: sim (MFMA) -> softmax -> attn [B,64] (cols 32..63 = 0) -------
__global__ __launch_bounds__(256) void k_mid2(const u16* __restrict__ h,
                                              const u16* __restrict__ pb,
                                              u16* __restrict__ ab) {
  __shared__ u16 attn_sm[4][16 * 32];
  const int tid = threadIdx.x;
  const int w = tid >> 6, lane = tid & 63;
  const int lm = lane & 15, lk = lane >> 4;
  const int row0 = blockIdx.x * 64 + w * 16;

  f32x4 zero = {0.f, 0.f, 0.f, 0.f};
  f32x4 acc0 = zero, acc1 = zero;
  float ss = 0.f;

  const u16* hrow = h + ((size_t)(row0 + lm) << 10) + lk * 8;
  const u16* pb0 = pb + (size_t)lm * DD + lk * 8;
  const u16* pb1 = pb + (size_t)(16 + lm) * DD + lk * 8;
#pragma unroll 4
  for (int k0 = 0; k0 < DD; k0 += 32) {
    bf16x8 af = *(const bf16x8*)(hrow + k0);
    bf16x8 b0 = *(const bf16x8*)(pb0 + k0);
    bf16x8 b1 = *(const bf16x8*)(pb1 + k0);
    acc0 = __builtin_amdgcn_mfma_f32_16x16x32_bf16(af, b0, acc0, 0, 0, 0);
    acc1 = __builtin_amdgcn_mfma_f32_16x16x32_bf16(af, b1, acc1, 0, 0, 0);
#pragma unroll
    for (int j = 0; j < 8; ++j) {
      float hv = bf2f((u16)af[j]);
      ss += hv * hv;
    }
  }
  ss += __shfl_xor(ss, 16);
  ss += __shfl_xor(ss, 32);
  float inv = 10.0f / fmaxf(sqrtf(ss), 1e-12f);

  float a0[4], a1[4];
#pragma unroll
  for (int r = 0; r < 4; ++r) {
    float invr = __shfl(inv, lk * 4 + r);
    float s0 = acc0[r] * invr;
    float s1 = acc1[r] * invr;
    float mr = fmaxf(s0, s1);
#pragma unroll
    for (int off = 1; off < 16; off <<= 1) mr = fmaxf(mr, __shfl_xor(mr, off));
    float e0 = expf(s0 - mr);
    float e1 = expf(s1 - mr);
    float sum = e0 + e1;
#pragma unroll
    for (int off = 1; off < 16; off <<= 1) sum += __shfl_xor(sum, off);
    float rs = 1.0f / sum;
    a0[r] = e0 * rs;
    a1[r] = e1 * rs;
  }

  u16* as = attn_sm[w];
#pragma unroll
  for (int r = 0; r < 4; ++r) {
    as[(lk * 4 + r) * 32 + lm] = f2bf(a0[r]);
    as[(lk * 4 + r) * 32 + 16 + lm] = f2bf(a1[r]);
  }
  __syncthreads();
  // write attn rows + zero pad: lane l -> row l>>2, 8-u16 chunk (l&3)
  int rr = lane >> 2, c8 = (lane & 3) << 3;
  int4 v = *(const int4*)(as + rr * 32 + c8);
  size_t orow = (size_t)(row0 + rr) * 64;
  *(int4*)(ab + orow + c8) = v;
  int4 z = {0, 0, 0, 0};
  *(int4*)(ab + orow + 32 + c8) = z;
}

// ---------------- LayerNorm: read y bf16 (low half of each out-row slot), write f32 ----
__global__ __launch_bounds__(256) void k_ln2(u16* __restrict__ ybase,
                                             float* __restrict__ out,
                                             const float* __restrict__ gamma,
                                             const float* __restrict__ beta) {
  __shared__ float sb[8];
  size_t row = blockIdx.x;
  int tid = threadIdx.x;
  ushort4 v4 = ((const ushort4*)(ybase + row * 2048))[tid];
  float y0 = bf2f(v4.x), y1 = bf2f(v4.y), y2 = bf2f(v4.z), y3 = bf2f(v4.w);
  float s = y0 + y1 + y2 + y3;
  float q = y0 * y0 + y1 * y1 + y2 * y2 + y3 * y3;
#pragma unroll
  for (int off = 32; off; off >>= 1) { s += __shfl_xor(s, off); q += __shfl_xor(q, off); }
  if ((tid & 63) == 0) { sb[tid >> 6] = s; sb[4 + (tid >> 6)] = q; }
  __syncthreads();  // also drains all loads before any store below
  s = sb[0] + sb[1] + sb[2] + sb[3];
  q = sb[4] + sb[5] + sb[6] + sb[7];
  float mu = s * (1.f / 1024.f);
  float var = q * (1.f / 1024.f) - mu * mu;
  float rstd = rsqrtf(var + 1e-5f);
  float4 g = ((const float4*)gamma)[tid];
  float4 b = ((const float4*)beta)[tid];
  float4 o;
  o.x = (y0 - mu) * rstd * g.x + b.x;
  o.y = (y1 - mu) * rstd * g.y + b.y;
  o.z = (y2 - mu) * rstd * g.z + b.z;
  o.w = (y3 - mu) * rstd * g.w + b.w;
  ((float4*)(out + (row << 10)))[tid] = o;
}

extern "C" void kernel_launch(void* const* d_in, const int* in_sizes, int n_in,
                              void* d_out, int out_size, void* d_ws, size_t ws_size,
                              hipStream_t stream) {
  const float* x      = (const float*)d_in[0];
  const float* Wi     = (const float*)d_in[1];
  const float* bi     = (const float*)d_in[2];
  const float* Wo     = (const float*)d_in[3];
  const float* bo     = (const float*)d_in[4];
  const float* gamma  = (const float*)d_in[5];
  const float* beta   = (const float*)d_in[6];
  const float* protos = (const float*)d_in[7];
  const int Brows = in_sizes[0] / DD;  // 65536

  u16* xb   = (u16*)d_ws;                        // [B, 1024] bf16
  u16* WiB  = xb + (size_t)Brows * 1024;         // [1024, 1024]
  u16* WoB  = WiB + (size_t)1024 * 1024;         // [1024, 1088]  (Wo1 | P2 | pad)
  u16* pb   = WoB + (size_t)1024 * 1088;         // [32, 1024] normalized
  u16* ab   = pb + (size_t)PP * DD;              // [B, 64] attn (cols 32..63 zero)
  u16* hbuf = (u16*)d_out;                       // h bf16 lives in d_out storage
  u16* ybuf = (u16*)d_out;                       // y bf16, u16-stride 2048 (low half of slots)

  k_convert<<<4096, 256, 0, stream>>>(x, xb, Brows * 256);
  k_convert<<<1024, 256, 0, stream>>>(Wi, WiB, 1024 * 1024 / 4);
  k_convert_wo<<<1024, 256, 0, stream>>>(Wo, WoB);
  k_proto_prep<<<PP, 256, 0, stream>>>(protos, pb);
  k_p2<<<1024, 256, 0, stream>>>(Wo, protos, WoB);

  const int nbn = 1024 / 256;                    // 4 col-blocks
  const int nwg = nbn * (Brows / 256);           // 1024 blocks (mod 8 == 0)

  // h = x @ Wi^T + bi   (K = 1024, 16 tiles)
  k_gemmF<0, 16><<<nwg, 512, 0, stream>>>(xb, xb, WiB, 1024, bi, nullptr,
                                          hbuf, nbn);
  // sim -> softmax -> attn
  k_mid2<<<Brows / 64, 256, 0, stream>>>(hbuf, pb, ab);
  // y = bf16(gelu(x @ Wo1^T + attn @ P2 + bo) + bf16(x))  (K = 1088, 17 tiles)
  k_gemmF<1, 17><<<nwg, 512, 0, stream>>>(xb, ab, WoB, 1088, bo, xb,
                                          ybuf, nbn);
  // LayerNorm: y bf16 -> out f32 (in-slot)
  k_ln2<<<Brows, 256, 0, stream>>>(ybuf, (float*)d_out, gamma, beta);
}

// Round 14
// 493.320 us; speedup vs baseline: 2.0047x; 1.0635x over previous
//
#include <hip/hip_runtime.h>
#include <hip/hip_bf16.h>
#include <math.h>

typedef unsigned short u16;
typedef __attribute__((ext_vector_type(8))) short bf16x8;
typedef __attribute__((ext_vector_type(4))) float f32x4;
typedef __attribute__((address_space(1))) unsigned int gu32;
typedef __attribute__((address_space(3))) unsigned int lu32;

#define DD 1024
#define PP 32

__device__ __forceinline__ u16 f2bf(float f) {
  unsigned u = __float_as_uint(f);
  unsigned r = u + 0x7fffu + ((u >> 16) & 1u);
  return (u16)(r >> 16);
}
__device__ __forceinline__ float bf2f(u16 h) {
  return __uint_as_float(((unsigned)h) << 16);
}

// tanh-GELU: 0.5 v (1 + tanh(0.7978845608 (v + 0.044715 v^3))); tanh via exp2+rcp.
__device__ __forceinline__ float gelu_t(float v) {
  float u = v + 0.044715f * v * v * v;
  float p = __builtin_amdgcn_exp2f(2.302590614f * u);  // e^{2*0.79788456*u}
  float th = 1.0f - 2.0f * __builtin_amdgcn_rcpf(p + 1.0f);
  return 0.5f * v * (1.0f + th);
}

// ---------------- conversions ----------------
__global__ __launch_bounds__(256) void k_convert(const float* __restrict__ in,
                                                 u16* __restrict__ out, int n4) {
  for (int i = blockIdx.x * 256 + threadIdx.x; i < n4; i += gridDim.x * 256) {
    float4 v = ((const float4*)in)[i];
    ushort4 o;
    o.x = f2bf(v.x); o.y = f2bf(v.y); o.z = f2bf(v.z); o.w = f2bf(v.w);
    ((ushort4*)out)[i] = o;
  }
}

// Wo [1024,2048] f32 -> WoB[n, 0:1024] bf16 (stride 1088)
__global__ __launch_bounds__(256) void k_convert_wo(const float* __restrict__ Wo,
                                                    u16* __restrict__ WoB) {
  int i = blockIdx.x * 256 + threadIdx.x;  // 1024*256
  int n = i >> 8, c4 = i & 255;
  float4 v = ((const float4*)(Wo + (size_t)n * 2048))[c4];
  ushort4 o;
  o.x = f2bf(v.x); o.y = f2bf(v.y); o.z = f2bf(v.z); o.w = f2bf(v.w);
  *(ushort4*)(WoB + (size_t)n * 1088 + c4 * 4) = o;
}

// prototypes [32,1024] f32 -> row-l2-normalized bf16 (for sim)
__global__ __launch_bounds__(256) void k_proto_prep(const float* __restrict__ protos,
                                                    u16* __restrict__ pb) {
  __shared__ float sb[4];
  int row = blockIdx.x, tid = threadIdx.x;
  float4 v = ((const float4*)(protos + row * DD))[tid];
  float q = v.x * v.x + v.y * v.y + v.z * v.z + v.w * v.w;
#pragma unroll
  for (int off = 32; off; off >>= 1) q += __shfl_xor(q, off);
  if ((tid & 63) == 0) sb[tid >> 6] = q;
  __syncthreads();
  q = sb[0] + sb[1] + sb[2] + sb[3];
  float inv = 1.0f / fmaxf(sqrtf(q), 1e-12f);
  ushort4 o;
  o.x = f2bf(v.x * inv); o.y = f2bf(v.y * inv); o.z = f2bf(v.z * inv); o.w = f2bf(v.w * inv);
  ((ushort4*)(pb + row * DD))[tid] = o;
}

// P2[n,p] = sum_d Wo[n,1024+d] * protos[p,d]  (f32) -> WoB[n, 1024+p] bf16; zero pad cols
__global__ __launch_bounds__(256) void k_p2(const float* __restrict__ Wo,
                                            const float* __restrict__ protos,
                                            u16* __restrict__ WoB) {
  __shared__ float swo[1024];
  int n = blockIdx.x, tid = threadIdx.x;
  ((float4*)swo)[tid] = ((const float4*)(Wo + (size_t)n * 2048 + 1024))[tid];
  __syncthreads();
  int w = tid >> 6, lane = tid & 63;
#pragma unroll
  for (int q = 0; q < 8; ++q) {
    int p = w * 8 + q;
    const float* pr = protos + (size_t)p * 1024 + lane * 16;
    const float* wv = swo + lane * 16;
    float d = 0.f;
#pragma unroll
    for (int j = 0; j < 16; ++j) d += wv[j] * pr[j];
#pragma unroll
    for (int off = 32; off; off >>= 1) d += __shfl_xor(d, off);
    if (lane == 0) WoB[(size_t)n * 1088 + 1024 + p] = f2bf(d);
  }
  if (tid < 32) WoB[(size_t)n * 1088 + 1056 + tid] = 0;
}

// ---------------- 256x256 bf16 GEMM (B^T layout), T2 swizzle, merged sync ----------------
// C[m,n] = sum_k A'[m,k] * Bm[n,k], A' = [A (lda 1024) | Aext (stride 64, K-tile 16)].
// EPI 1: C = bf16(gelu(acc+bias[n]) + bf2f(residb[m*1024+n])) -> u16*, u16-stride 2048
//        (y bf16 packed into the low half of each f32 out-row slot); LDS-transposed stores.
// EPI 2: h = acc + bias never leaves the CU: per-wave eb holds the h chunk; compute
//        ||h||^2 partials -> ssp[B][16] (bn*4+wn) and sim partials = h @ pn^T via 32
//        extra MFMAs; wn-reduce through LDS -> simp[B][4][32] (bn).
#define GLL(gsrc, ldst) __builtin_amdgcn_global_load_lds((gu32*)(gsrc), (lu32*)(ldst), 16, 0, 0)

template <int EPI, int NT>
__global__ __launch_bounds__(512, 2) void k_gemmF(const u16* __restrict__ A,
                                                  const u16* __restrict__ Aext,
                                                  const u16* __restrict__ Bm, int bstride,
                                                  const float* __restrict__ bias,
                                                  const u16* __restrict__ residb,
                                                  u16* __restrict__ Cout,
                                                  int nbn,
                                                  const u16* __restrict__ pbn,
                                                  float* __restrict__ simp,
                                                  float* __restrict__ ssp) {
  __shared__ u16 Lsh[65536];  // [A dbuf 32768 | B dbuf 32768] u16; reused by epilogue
#define ALS(bufv, idx) (Lsh + (bufv) * 16384 + (idx))
#define BLS(bufv, idx) (Lsh + 32768 + (bufv) * 16384 + (idx))
  const int tid = threadIdx.x;
  const int wid = tid >> 6, lane = tid & 63;
  const int wm = wid >> 2, wn = wid & 3;
  const int lm = lane & 15, lk = lane >> 4;

  const int scol_sw = (((lane & 7) ^ ((lane >> 3) & 7)) << 3);
  const int srow = lane >> 3;

  // XCD chunked swizzle (nwg % 8 == 0)
  int g = blockIdx.x;
  int cpx = gridDim.x >> 3;
  int lin = (g & 7) * cpx + (g >> 3);
  int bn = lin % nbn, bm = lin / nbn;
  const size_t bmBase = (size_t)bm * 256;
  const size_t bnBase = (size_t)bn * 256;

  f32x4 acc[8][4];
#pragma unroll
  for (int i = 0; i < 8; ++i)
#pragma unroll
    for (int j = 0; j < 4; ++j) acc[i][j] = (f32x4){0.f, 0.f, 0.f, 0.f};

  bf16x8 a[4][2], b0[2][2], b1[2][2];

#define STAGE_A(bufv, kt, mh) do {                                              \
    int arow = (mh) * 64 + wid * 8 + srow;                                      \
    const u16 *ap0, *ap1;                                                       \
    if ((kt) < 16) {                                                            \
      ap0 = A + (bmBase + arow) * (size_t)1024 + scol_sw + (kt) * 64;           \
      ap1 = A + (bmBase + 128 + arow) * (size_t)1024 + scol_sw + (kt) * 64;     \
    } else {                                                                    \
      ap0 = Aext + (bmBase + arow) * (size_t)64 + scol_sw;                      \
      ap1 = Aext + (bmBase + 128 + arow) * (size_t)64 + scol_sw;                \
    }                                                                           \
    GLL(ap0, ALS(bufv, ((mh) * 64 + wid * 8) * 64));                            \
    GLL(ap1, ALS(bufv, (128 + (mh) * 64 + wid * 8) * 64));                      \
  } while (0)

#define STAGE_B(bufv, kt, nh) do {                                              \
    int br0 = ((wid >> 2) << 6) + (nh) * 32 + ((wid & 3) << 3);                 \
    int bcol = scol_sw + (kt) * 64;                                             \
    GLL(Bm + (bnBase + br0 + srow) * (size_t)bstride + bcol, BLS(bufv, br0 * 64)); \
    GLL(Bm + (bnBase + 128 + br0 + srow) * (size_t)bstride + bcol, BLS(bufv, (128 + br0) * 64)); \
  } while (0)

#define LOAD_A(bufv, mh) do {                                                   \
    _Pragma("unroll") for (int mi2 = 0; mi2 < 4; ++mi2) {                       \
      int row = wm * 128 + (mh) * 64 + mi2 * 16 + lm;                           \
      _Pragma("unroll") for (int kk = 0; kk < 2; ++kk)                          \
        a[mi2][kk] = *(const bf16x8*)ALS(bufv, row * 64 + ((kk * 32 + lk * 8) ^ ((lm & 7) << 3))); \
    }                                                                           \
  } while (0)

#define LOAD_B(dst, bufv, nh) do {                                              \
    _Pragma("unroll") for (int ni2 = 0; ni2 < 2; ++ni2) {                       \
      int row = wn * 64 + (nh) * 32 + ni2 * 16 + lm;                            \
      _Pragma("unroll") for (int kk = 0; kk < 2; ++kk)                          \
        dst[ni2][kk] = *(const bf16x8*)BLS(bufv, row * 64 + ((kk * 32 + lk * 8) ^ ((lm & 7) << 3))); \
    }                                                                           \
  } while (0)

#define BARRIER do { __builtin_amdgcn_s_barrier(); asm volatile("" ::: "memory"); } while (0)

#define MFMA_Q(bb, mh, nh) do {                                                 \
    __builtin_amdgcn_s_setprio(1);                                              \
    _Pragma("unroll") for (int mi2 = 0; mi2 < 4; ++mi2)                         \
    _Pragma("unroll") for (int ni2 = 0; ni2 < 2; ++ni2)                         \
    _Pragma("unroll") for (int kk = 0; kk < 2; ++kk)                            \
      acc[(mh) * 4 + mi2][(nh) * 2 + ni2] = __builtin_amdgcn_mfma_f32_16x16x32_bf16( \
          a[mi2][kk], bb[ni2][kk], acc[(mh) * 4 + mi2][(nh) * 2 + ni2], 0, 0, 0); \
    __builtin_amdgcn_s_setprio(0);                                              \
  } while (0)

#define TILE(T, P) do {                                                         \
    asm volatile("s_waitcnt vmcnt(0)" ::: "memory");                            \
    BARRIER;                                                                    \
    if ((T) + 1 < NT) {                                                         \
      STAGE_A((P) ^ 1, (T) + 1, 0); STAGE_B((P) ^ 1, (T) + 1, 0);               \
      STAGE_A((P) ^ 1, (T) + 1, 1); STAGE_B((P) ^ 1, (T) + 1, 1);               \
    }                                                                           \
    LOAD_A(P, 0); LOAD_B(b0, P, 0);                                             \
    MFMA_Q(b0, 0, 0);                                                           \
    LOAD_B(b1, P, 1);                                                           \
    MFMA_Q(b1, 0, 1);                                                           \
    LOAD_A(P, 1);                                                               \
    MFMA_Q(b1, 1, 1);                                                           \
    MFMA_Q(b0, 1, 0);                                                           \
  } while (0)

  // prologue: stage tile0 into buf0
  STAGE_A(0, 0, 0); STAGE_B(0, 0, 0); STAGE_A(0, 0, 1); STAGE_B(0, 0, 1);

#pragma unroll
  for (int T = 0; T + 1 < NT; T += 2) {
    TILE(T, 0);
    TILE(T + 1, 1);
  }
  if (NT & 1) TILE(NT - 1, 0);  // odd NT tail (parity: NT-1 even)

  // ---- epilogue ----
  __syncthreads();  // all waves done reading the K-loop tiles
  u16* eb = Lsh + wid * 4608;  // per-wave 64 x 72 u16 (16B-aligned rows)
  const size_t gr0 = bmBase + wm * 128;
  const int gc0 = (int)bnBase + wn * 64;

  if (EPI == 2) {
    // sim/norm fused epilogue: h stays on-CU
    bf16x8 bp[2][2];
#pragma unroll
    for (int ph = 0; ph < 2; ++ph)
#pragma unroll
      for (int kk = 0; kk < 2; ++kk)
        bp[ph][kk] = *(const bf16x8*)(pbn + (size_t)(ph * 16 + lm) * 1024 + gc0 + kk * 32 + lk * 8);
    f32x4 sa[2][4][2];
#pragma unroll
    for (int ch = 0; ch < 2; ++ch) {
      // scatter h = acc + bias (bf16) into eb (swizzled)
#pragma unroll
      for (int mi2 = 0; mi2 < 4; ++mi2) {
        int mi = ch * 4 + mi2;
#pragma unroll
        for (int ni = 0; ni < 4; ++ni) {
          int col = ni * 16 + lm;
          float bv = bias[gc0 + ni * 16 + lm];
#pragma unroll
          for (int r = 0; r < 4; ++r) {
            int rowL = mi2 * 16 + lk * 4 + r;
            eb[rowL * 72 + (col ^ (((rowL >> 2) & 3) << 3))] = f2bf(acc[mi][ni][r] + bv);
          }
        }
      }
      // A-frags from eb (row=lm, k=lk*8+j), ||h||^2 partial, sim MFMAs
#pragma unroll
      for (int rg = 0; rg < 4; ++rg) {
        int rowL = rg * 16 + lm;
        int swz = ((lm >> 2) & 3) << 3;
        bf16x8 af0 = *(const bf16x8*)&eb[rowL * 72 + ((lk * 8) ^ swz)];
        bf16x8 af1 = *(const bf16x8*)&eb[rowL * 72 + ((32 + lk * 8) ^ swz)];
        float sq = 0.f;
#pragma unroll
        for (int j = 0; j < 8; ++j) {
          float h0 = bf2f((u16)af0[j]), h1 = bf2f((u16)af1[j]);
          sq += h0 * h0 + h1 * h1;
        }
        sq += __shfl_xor(sq, 16);
        sq += __shfl_xor(sq, 32);
        if (lk == 0)
          ssp[(gr0 + ch * 64 + rg * 16 + lm) * 16 + bn * 4 + wn] = sq;
        f32x4 z = {0.f, 0.f, 0.f, 0.f};
        f32x4 s0 = __builtin_amdgcn_mfma_f32_16x16x32_bf16(af0, bp[0][0], z, 0, 0, 0);
        s0 = __builtin_amdgcn_mfma_f32_16x16x32_bf16(af1, bp[0][1], s0, 0, 0, 0);
        f32x4 s1 = __builtin_amdgcn_mfma_f32_16x16x32_bf16(af0, bp[1][0], z, 0, 0, 0);
        s1 = __builtin_amdgcn_mfma_f32_16x16x32_bf16(af1, bp[1][1], s1, 0, 0, 0);
        sa[ch][rg][0] = s0;
        sa[ch][rg][1] = s1;
      }
    }
    __syncthreads();            // all waves done reading their eb
    float* part = (float*)Lsh;  // [4 wn][256 rows][32 p] f32 = 128 KB exactly
#pragma unroll
    for (int ch = 0; ch < 2; ++ch)
#pragma unroll
      for (int rg = 0; rg < 4; ++rg)
#pragma unroll
        for (int ph = 0; ph < 2; ++ph)
#pragma unroll
          for (int r = 0; r < 4; ++r) {
            int row = wm * 128 + ch * 64 + rg * 16 + lk * 4 + r;
            part[wn * 8192 + row * 32 + ph * 16 + lm] = sa[ch][rg][ph][r];
          }
    __syncthreads();
    // wn-reduce + coalesced global write of sim partials (per bn)
    for (int i = tid; i < 8192; i += 512) {
      int row = i >> 5, p = i & 31;
      float s = part[row * 32 + p] + part[8192 + row * 32 + p] +
                part[16384 + row * 32 + p] + part[24576 + row * 32 + p];
      simp[(bmBase + row) * 128 + (size_t)bn * 32 + p] = s;
    }
  } else {
    // EPI == 1: gelu + resid, LDS transpose -> coalesced 16B stores
#pragma unroll
    for (int ch = 0; ch < 2; ++ch) {
#pragma unroll
      for (int mi2 = 0; mi2 < 4; ++mi2) {
        int mi = ch * 4 + mi2;
#pragma unroll
        for (int ni = 0; ni < 4; ++ni) {
          int col = ni * 16 + lm;
          float bv = bias[gc0 + ni * 16 + lm];
#pragma unroll
          for (int r = 0; r < 4; ++r) {
            int rowL = mi2 * 16 + lk * 4 + r;
            float v = acc[mi][ni][r] + bv;
            v = gelu_t(v);
            eb[rowL * 72 + (col ^ (((rowL >> 2) & 3) << 3))] = f2bf(v);
          }
        }
      }
#pragma unroll
      for (int i = 0; i < 8; ++i) {
        int rowL = i * 8 + (lane >> 3);
        int c8 = (lane & 7) * 8;
        bf16x8 yv = *(const bf16x8*)&eb[rowL * 72 + (c8 ^ (((rowL >> 2) & 3) << 3))];
        size_t grow = gr0 + ch * 64 + rowL;
        bf16x8 rv = *(const bf16x8*)(residb + grow * 1024 + gc0 + c8);
        bf16x8 ov;
#pragma unroll
        for (int j = 0; j < 8; ++j)
          ov[j] = (short)f2bf(bf2f((u16)yv[j]) + bf2f((u16)rv[j]));
        *(bf16x8*)(Cout + grow * 2048 + gc0 + c8) = ov;
      }
    }
  }
#undef STAGE_A
#undef STAGE_B
#undef LOAD_A
#undef LOAD_B
#undef MFMA_Q
#undef TILE
#undef BARRIER
#undef ALS
#undef BLS
}

// ---------------- softmax over the 4 bn sim-partials -> ab [B,64] bf16 ----------------
__global__ __launch_bounds__(256) void k_soft(const float* __restrict__ simp,
                                              const float* __restrict__ ssp,
                                              u16* __restrict__ ab) {
  const int wv = threadIdx.x >> 6, lane = threadIdx.x & 63;
  int rowBase = blockIdx.x * 32 + wv * 8;
#pragma unroll
  for (int i = 0; i < 8; ++i) {
    int row = rowBase + i;
    const float* sp = simp + (size_t)row * 128;
    float v = sp[lane] + sp[64 + lane];
    v += __shfl_xor(v, 32);  // every lane: sim[lane & 31] (full over 4 bn)
    float ssv = (lane < 16) ? ssp[(size_t)row * 16 + lane] : 0.f;
    ssv += __shfl_xor(ssv, 1); ssv += __shfl_xor(ssv, 2);
    ssv += __shfl_xor(ssv, 4); ssv += __shfl_xor(ssv, 8);
    float ss = __shfl(ssv, 0);
    float inv = 10.0f / fmaxf(sqrtf(ss), 1e-12f);
    float s = v * inv;
    float m = s;
#pragma unroll
    for (int off = 1; off < 32; off <<= 1) m = fmaxf(m, __shfl_xor(m, off));
    float e = expf(s - m);
    float sum = e;
#pragma unroll
    for (int off = 1; off < 32; off <<= 1) sum += __shfl_xor(sum, off);
    float a = e / sum;
    ab[(size_t)row * 64 + lane] = (lane < 32) ? f2bf(a) : (u16)0;
  }
}

// ---------------- LayerNorm: read y bf16 (low half of each out-row slot), write f32 ----
__global__ __launch_bounds__(256) void k_ln2(u16* __restrict__ ybase,
                                             float* __restrict__ out,
                                             const float* __restrict__ gamma,
                                             const float* __restrict__ beta) {
  __shared__ float sb[8];
  size_t row = blockIdx.x;
  int tid = threadIdx.x;
  ushort4 v4 = ((const ushort4*)(ybase + row * 2048))[tid];
  float y0 = bf2f(v4.x), y1 = bf2f(v4.y), y2 = bf2f(v4.z), y3 = bf2f(v4.w);
  float s = y0 + y1 + y2 + y3;
  float q = y0 * y0 + y1 * y1 + y2 * y2 + y3 * y3;
#pragma unroll
  for (int off = 32; off; off >>= 1) { s += __shfl_xor(s, off); q += __shfl_xor(q, off); }
  if ((tid & 63) == 0) { sb[tid >> 6] = s; sb[4 + (tid >> 6)] = q; }
  __syncthreads();  // also drains all loads before any store below
  s = sb[0] + sb[1] + sb[2] + sb[3];
  q = sb[4] + sb[5] + sb[6] + sb[7];
  float mu = s * (1.f / 1024.f);
  float var = q * (1.f / 1024.f) - mu * mu;
  float rstd = rsqrtf(var + 1e-5f);
  float4 g = ((const float4*)gamma)[tid];
  float4 b = ((const float4*)beta)[tid];
  float4 o;
  o.x = (y0 - mu) * rstd * g.x + b.x;
  o.y = (y1 - mu) * rstd * g.y + b.y;
  o.z = (y2 - mu) * rstd * g.z + b.z;
  o.w = (y3 - mu) * rstd * g.w + b.w;
  ((float4*)(out + (row << 10)))[tid] = o;
}

extern "C" void kernel_launch(void* const* d_in, const int* in_sizes, int n_in,
                              void* d_out, int out_size, void* d_ws, size_t ws_size,
                              hipStream_t stream) {
  const float* x      = (const float*)d_in[0];
  const float* Wi     = (const float*)d_in[1];
  const float* bi     = (const float*)d_in[2];
  const float* Wo     = (const float*)d_in[3];
  const float* bo     = (const float*)d_in[4];
  const float* gamma  = (const float*)d_in[5];
  const float* beta   = (const float*)d_in[6];
  const float* protos = (const float*)d_in[7];
  const int Brows = in_sizes[0] / DD;  // 65536

  u16* xb   = (u16*)d_ws;                        // [B, 1024] bf16
  u16* WiB  = xb + (size_t)Brows * 1024;         // [1024, 1024]
  u16* WoB  = WiB + (size_t)1024 * 1024;         // [1024, 1088]  (Wo1 | P2 | pad)
  u16* pb   = WoB + (size_t)1024 * 1088;         // [32, 1024] normalized
  u16* ab   = pb + (size_t)PP * DD;              // [B, 64] attn (cols 32..63 zero)
  float* simp = (float*)(ab + (size_t)Brows * 64);   // [B, 4, 32] sim partials (per bn)
  float* ssp  = simp + (size_t)Brows * 128;          // [B, 16] ||h||^2 partials (bn*4+wn)
  u16* ybuf = (u16*)d_out;                       // y bf16, u16-stride 2048 (low half of slots)

  k_convert<<<4096, 256, 0, stream>>>(x, xb, Brows * 256);
  k_convert<<<1024, 256, 0, stream>>>(Wi, WiB, 1024 * 1024 / 4);
  k_convert_wo<<<1024, 256, 0, stream>>>(Wo, WoB);
  k_proto_prep<<<PP, 256, 0, stream>>>(protos, pb);
  k_p2<<<1024, 256, 0, stream>>>(Wo, protos, WoB);

  const int nbn = 1024 / 256;                    // 4 col-blocks
  const int nwg = nbn * (Brows / 256);           // 1024 blocks (mod 8 == 0)

  // h = x @ Wi^T + bi fused with sim/norm partials (h never hits HBM)
  k_gemmF<2, 16><<<nwg, 512, 0, stream>>>(xb, xb, WiB, 1024, bi, nullptr,
                                          nullptr, nbn, pb, simp, ssp);
  // softmax over partials -> attn
  k_soft<<<Brows / 32, 256, 0, stream>>>(simp, ssp, ab);
  // y = bf16(gelu(x @ Wo1^T + attn @ P2 + bo) + bf16(x))  (K = 1088, 17 tiles)
  k_gemmF<1, 17><<<nwg, 512, 0, stream>>>(xb, ab, WoB, 1088, bo, xb,
                                          ybuf, nbn, nullptr, nullptr, nullptr);
  // LayerNorm: y bf16 -> out f32 (in-slot)
  k_ln2<<<Brows, 256, 0, stream>>>(ybuf, (float*)d_out, gamma, beta);
}